// Round 10
// baseline (1044.651 us; speedup 1.0000x reference)
//
#include <hip/hip_runtime.h>

#define N_NODES 100000
#define N_EDGES 1000000
#define D 128
#define NB ((N_NODES + 255) / 256)   // 391 scan blocks
#define LN_EPS 1e-5f
#define CNT_EPS 1e-10f
#define SPW 408   // LDS stride per W-col in bf16 (816B; 204 words = 12 mod 32 -> <=2-way)

typedef __bf16 bf16x8 __attribute__((ext_vector_type(8)));
typedef __bf16 bf16x4 __attribute__((ext_vector_type(4)));
typedef float  f32x4  __attribute__((ext_vector_type(4)));

#define ROWRED(v) { v += __shfl_xor(v, 1); v += __shfl_xor(v, 2); \
                    v += __shfl_xor(v, 4); v += __shfl_xor(v, 8); }

// ---------------------------------------------------------------------------
// Prep: Wt[j][k] = bf16(We[k][j] + (k==j))   (128x384, residual folded in)
//       Wtn[j][k] = bf16(Wn[k][j])           (128x256)
// ---------------------------------------------------------------------------
__global__ void prep_w(const float* __restrict__ We, const float* __restrict__ Wn,
                       __bf16* __restrict__ Wt, __bf16* __restrict__ Wtn)
{
    const int t = blockIdx.x * 256 + threadIdx.x;
    if (t < 128 * 384) {
        const int j = t / 384, k = t % 384;
        Wt[t] = (__bf16)(We[(size_t)k * 128 + j] + ((k == j) ? 1.0f : 0.0f));
    } else if (t < 128 * 384 + 128 * 256) {
        const int u = t - 128 * 384;
        const int j = u / 256, k = u % 256;
        Wtn[u] = (__bf16)Wn[(size_t)k * 128 + j];
    }
}

// ---------------------------------------------------------------------------
// Edge update via swapped-operand MFMA, max load concurrency:
//  - ALL 12 gathers (24 dwordx4/lane, 96 VGPR) issued BEFORE W-stage+barrier;
//    occupancy is LDS-capped (1 block/CU) so the VGPRs are free.
//  - block = 1024 thr (16 waves = 50% occ cap); each wave owns 16 edges.
//  - W (128x384, residual folded) staged once, padded stride (conflict-free).
//  - compute = 96 MFMA burst; epilogue bias+LN (xor16/32) + f32 & bf16 stores.
// ---------------------------------------------------------------------------
__launch_bounds__(1024)
__global__ void edge_kernel(const float* __restrict__ nodef,
                            const float* __restrict__ edgef,
                            const int*   __restrict__ eidx,
                            const __bf16* __restrict__ Wt,
                            const float* __restrict__ be,
                            const float* __restrict__ gamma_e,
                            const float* __restrict__ beta_e,
                            float* __restrict__ new_edges,
                            __bf16* __restrict__ sh)
{
    __shared__ __bf16 Ws[128 * SPW];          // 104448 B

    const int tid  = threadIdx.x;
    const int wid  = tid >> 6;
    const int lane = tid & 63;
    const int li   = lane & 15;
    const int lg   = lane >> 4;

    const int erow = blockIdx.x * 256 + wid * 16 + li;   // this lane's edge
    const int e    = min(erow, N_EDGES - 1);
    const int sn   = eidx[e];
    const int tn   = eidx[N_EDGES + e];

    const float* p0 = edgef + (size_t)e  * D + lg * 8;
    const float* p1 = nodef + (size_t)sn * D + lg * 8;
    const float* p2 = nodef + (size_t)tn * D + lg * 8;

    // ---- issue ALL gathers first: 24 dwordx4 in flight per lane ----
    float4 u[12][2];
    #pragma unroll
    for (int kt = 0; kt < 4; ++kt) {
        u[kt][0] = *(const float4*)(p0 + kt * 32);
        u[kt][1] = *(const float4*)(p0 + kt * 32 + 4);
    }
    #pragma unroll
    for (int kt = 0; kt < 4; ++kt) {
        u[4 + kt][0] = *(const float4*)(p1 + kt * 32);
        u[4 + kt][1] = *(const float4*)(p1 + kt * 32 + 4);
    }
    #pragma unroll
    for (int kt = 0; kt < 4; ++kt) {
        u[8 + kt][0] = *(const float4*)(p2 + kt * 32);
        u[8 + kt][1] = *(const float4*)(p2 + kt * 32 + 4);
    }

    // ---- stage W once: 6144 16B-chunks, coalesced read, padded write ----
    #pragma unroll
    for (int i = 0; i < 6; ++i) {
        const int f   = i * 1024 + tid;
        const int col = f / 48;
        const int kc  = f - col * 48;
        *(bf16x8*)&Ws[col * SPW + kc * 8] = *(const bf16x8*)(Wt + (size_t)f * 8);
    }
    __syncthreads();                           // the only barrier

    f32x4 acc[8];
    const f32x4 zero = {0.f, 0.f, 0.f, 0.f};
    #pragma unroll
    for (int mt = 0; mt < 8; ++mt) acc[mt] = zero;

    #pragma unroll
    for (int kt = 0; kt < 12; ++kt) {
        bf16x8 bf;
        bf[0] = (__bf16)u[kt][0].x; bf[1] = (__bf16)u[kt][0].y;
        bf[2] = (__bf16)u[kt][0].z; bf[3] = (__bf16)u[kt][0].w;
        bf[4] = (__bf16)u[kt][1].x; bf[5] = (__bf16)u[kt][1].y;
        bf[6] = (__bf16)u[kt][1].z; bf[7] = (__bf16)u[kt][1].w;
        #pragma unroll
        for (int mt = 0; mt < 8; ++mt) {
            const bf16x8 wf =
                *(const bf16x8*)&Ws[(mt * 16 + li) * SPW + kt * 32 + lg * 8];
            acc[mt] = __builtin_amdgcn_mfma_f32_16x16x32_bf16(wf, bf, acc[mt], 0, 0, 0);
        }
    }

    // ---- epilogue: bias + LN (reduce over lg) + store ----
    float xs[8][4];
    float s = 0.f;
    #pragma unroll
    for (int mt = 0; mt < 8; ++mt) {
        const float4 b4 = *(const float4*)(be + mt * 16 + lg * 4);
        xs[mt][0] = acc[mt][0] + b4.x;
        xs[mt][1] = acc[mt][1] + b4.y;
        xs[mt][2] = acc[mt][2] + b4.z;
        xs[mt][3] = acc[mt][3] + b4.w;
        s += (xs[mt][0] + xs[mt][1]) + (xs[mt][2] + xs[mt][3]);
    }
    s += __shfl_xor(s, 16);
    s += __shfl_xor(s, 32);
    const float mean = s * 0.0078125f;
    float vs = 0.f;
    #pragma unroll
    for (int mt = 0; mt < 8; ++mt) {
        #pragma unroll
        for (int r = 0; r < 4; ++r) {
            const float d_ = xs[mt][r] - mean;
            vs = fmaf(d_, d_, vs);
        }
    }
    vs += __shfl_xor(vs, 16);
    vs += __shfl_xor(vs, 32);
    const float rstd = rsqrtf(vs * 0.0078125f + LN_EPS);

    if (erow < N_EDGES) {
        const size_t eb = (size_t)erow * D;
        #pragma unroll
        for (int mt = 0; mt < 8; ++mt) {
            const float4 g4 = *(const float4*)(gamma_e + mt * 16 + lg * 4);
            const float4 t4 = *(const float4*)(beta_e  + mt * 16 + lg * 4);
            float4 y;
            y.x = fmaf((xs[mt][0] - mean) * rstd, g4.x, t4.x);
            y.y = fmaf((xs[mt][1] - mean) * rstd, g4.y, t4.y);
            y.z = fmaf((xs[mt][2] - mean) * rstd, g4.z, t4.z);
            y.w = fmaf((xs[mt][3] - mean) * rstd, g4.w, t4.w);
            *(float4*)(new_edges + eb + mt * 16 + lg * 4) = y;
            if (sh) {
                bf16x4 hv;
                hv[0] = (__bf16)y.x; hv[1] = (__bf16)y.y;
                hv[2] = (__bf16)y.z; hv[3] = (__bf16)y.w;
                *(bf16x4*)&sh[eb + mt * 16 + lg * 4] = hv;
            }
        }
    }
}

// ---------------------------------------------------------------------------
// Node update via MFMA (LDS 2-phase; only 782 blocks, not the bottleneck).
// ---------------------------------------------------------------------------
#define ESTORE(buf) { \
    bf16x8 a0, a1; \
    a0[0] = (__bf16)v0.x; a0[1] = (__bf16)v0.y; a0[2] = (__bf16)v0.z; a0[3] = (__bf16)v0.w; \
    a0[4] = (__bf16)v1.x; a0[5] = (__bf16)v1.y; a0[6] = (__bf16)v1.z; a0[7] = (__bf16)v1.w; \
    a1[0] = (__bf16)v2.x; a1[1] = (__bf16)v2.y; a1[2] = (__bf16)v2.z; a1[3] = (__bf16)v2.w; \
    a1[4] = (__bf16)v3.x; a1[5] = (__bf16)v3.y; a1[6] = (__bf16)v3.z; a1[7] = (__bf16)v3.w; \
    *(bf16x8*)&NAs[buf][lrow][lhalf * 16]     = a0; \
    *(bf16x8*)&NAs[buf][lrow][lhalf * 16 + 8] = a1; \
    *(bf16x8*)&NBt[buf][lrow][lhalf * 16]     = wb0; \
    *(bf16x8*)&NBt[buf][lrow][lhalf * 16 + 8] = wb1; }

#define EMFMA(buf) { \
    const bf16x8 af0 = *(const bf16x8*)&NAs[buf][wid * 32 + li][k0]; \
    const bf16x8 af1 = *(const bf16x8*)&NAs[buf][wid * 32 + 16 + li][k0]; \
    _Pragma("unroll") \
    for (int nt = 0; nt < 8; ++nt) { \
        const bf16x8 bfr = *(const bf16x8*)&NBt[buf][nt * 16 + li][k0]; \
        acc[0][nt] = __builtin_amdgcn_mfma_f32_16x16x32_bf16(af0, bfr, acc[0][nt], 0, 0, 0); \
        acc[1][nt] = __builtin_amdgcn_mfma_f32_16x16x32_bf16(af1, bfr, acc[1][nt], 0, 0, 0); \
    } }

#define NLOAD(kt) { \
    const float* ab = ((kt) < 4) ? nodp + (kt) * 32 : aggp + ((kt) - 4) * 32; \
    v0 = ((const float4*)ab)[0]; v1 = ((const float4*)ab)[1]; \
    v2 = ((const float4*)ab)[2]; v3 = ((const float4*)ab)[3]; \
    wb0 = *(const bf16x8*)(wbp + (kt) * 32); \
    wb1 = *(const bf16x8*)(wbp + (kt) * 32 + 8); }

__launch_bounds__(256)
__global__ void node_kernel(const float* __restrict__ nodef,
                            const __bf16* __restrict__ Wtn,
                            const float* __restrict__ bn,
                            const float* __restrict__ gamma_n,
                            const float* __restrict__ beta_n,
                            const float* __restrict__ edge_mean,
                            float* __restrict__ new_nodes)
{
    __shared__ __bf16 NAs[2][128][40];
    __shared__ __bf16 NBt[2][128][40];

    const int tid = threadIdx.x;
    const int n0  = blockIdx.x * 128;

    const int lrow  = tid >> 1;
    const int lhalf = tid & 1;
    const size_t nclamp = (size_t)min(n0 + lrow, N_NODES - 1);

    const float* nodp = nodef     + nclamp * D + lhalf * 16;
    const float* aggp = edge_mean + nclamp * D + lhalf * 16;
    const __bf16* wbp = Wtn + (size_t)lrow * 256 + lhalf * 16;

    const int wid  = tid >> 6;
    const int lane = tid & 63;
    const int li   = lane & 15;
    const int lg   = lane >> 4;
    const int k0   = lg * 8;

    f32x4 acc[2][8];
    const f32x4 zero = {0.f, 0.f, 0.f, 0.f};
    #pragma unroll
    for (int m = 0; m < 2; ++m)
        #pragma unroll
        for (int n = 0; n < 8; ++n) acc[m][n] = zero;

    float4 v0, v1, v2, v3;
    bf16x8 wb0, wb1;

    NLOAD(0);
    ESTORE(0);
    #pragma unroll
    for (int kt = 0; kt < 8; ++kt) {
        const int cur = kt & 1;
        if (kt < 7) NLOAD(kt + 1);
        __syncthreads();
        EMFMA(cur);
        if (kt < 7) ESTORE(cur ^ 1);
    }

    float g[8], bt_[8], bias[8];
    #pragma unroll
    for (int nt = 0; nt < 8; ++nt) {
        const int col = nt * 16 + li;
        g[nt]    = gamma_n[col];
        bt_[nt]  = beta_n[col];
        bias[nt] = bn[col];
    }

    #pragma unroll
    for (int mt = 0; mt < 2; ++mt) {
        #pragma unroll
        for (int r = 0; r < 4; ++r) {
            const int rl = wid * 32 + mt * 16 + lg * 4 + r;
            const int n  = n0 + rl;
            const size_t nc = (size_t)min(n, N_NODES - 1);
            float x[8];
            float s = 0.f;
            #pragma unroll
            for (int nt = 0; nt < 8; ++nt) {
                x[nt] = acc[mt][nt][r] + bias[nt] + nodef[nc * D + nt * 16 + li];
                s += x[nt];
            }
            ROWRED(s);
            const float mean = s * 0.0078125f;
            float vs = 0.f;
            #pragma unroll
            for (int nt = 0; nt < 8; ++nt) { const float d_ = x[nt] - mean; vs = fmaf(d_, d_, vs); }
            ROWRED(vs);
            const float rstd = rsqrtf(vs * 0.0078125f + LN_EPS);
            if (n < N_NODES) {
                #pragma unroll
                for (int nt = 0; nt < 8; ++nt)
                    new_nodes[nc * D + nt * 16 + li] =
                        fmaf((x[nt] - mean) * rstd, g[nt], bt_[nt]);
            }
        }
    }
}

// ---------------------------------------------------------------------------
// CSR build: count -> hierarchical scan -> fill
// ---------------------------------------------------------------------------
__global__ void count_kernel(const int* __restrict__ eidx, int* __restrict__ cnt)
{
    const int i = blockIdx.x * blockDim.x + threadIdx.x;
    if (i < 2 * N_EDGES) atomicAdd(&cnt[eidx[i]], 1);
}

__global__ void scan1(const int* __restrict__ cnt, int* __restrict__ excl,
                      int* __restrict__ bsum)
{
    const int tid = threadIdx.x, lane = tid & 63, wid = tid >> 6;
    const int i = blockIdx.x * 256 + tid;
    const int v = (i < N_NODES) ? cnt[i] : 0;
    int x = v;
    #pragma unroll
    for (int s = 1; s < 64; s <<= 1) { const int t = __shfl_up(x, s); if (lane >= s) x += t; }
    __shared__ int ws[4], wb[4];
    if (lane == 63) ws[wid] = x;
    __syncthreads();
    if (tid == 0) {
        int run = 0;
        #pragma unroll
        for (int w = 0; w < 4; ++w) { wb[w] = run; run += ws[w]; }
        bsum[blockIdx.x] = run;
    }
    __syncthreads();
    if (i < N_NODES) excl[i] = wb[wid] + x - v;
}

__global__ void scan2(int* __restrict__ bsum, int* __restrict__ offs)
{
    __shared__ int ws[4], wb[4];
    __shared__ int sbase;
    const int tid = threadIdx.x, lane = tid & 63, wid = tid >> 6;
    if (tid == 0) sbase = 0;
    __syncthreads();
    for (int chunk = 0; chunk < NB; chunk += 256) {
        const int i = chunk + tid;
        const int v = (i < NB) ? bsum[i] : 0;
        int x = v;
        #pragma unroll
        for (int s = 1; s < 64; s <<= 1) { const int t = __shfl_up(x, s); if (lane >= s) x += t; }
        if (lane == 63) ws[wid] = x;
        __syncthreads();
        if (tid == 0) {
            int run = sbase;
            #pragma unroll
            for (int w = 0; w < 4; ++w) { wb[w] = run; run += ws[w]; }
            sbase = run;
        }
        __syncthreads();
        if (i < NB) bsum[i] = wb[wid] + x - v;
        __syncthreads();
    }
    if (tid == 0) offs[N_NODES] = sbase;
}

__global__ void scan3(const int* __restrict__ excl, const int* __restrict__ bsum,
                      int* __restrict__ offs, int* __restrict__ cursor)
{
    const int i = blockIdx.x * 256 + threadIdx.x;
    if (i < N_NODES) {
        const int o = excl[i] + bsum[i >> 8];
        offs[i] = o;
        cursor[i] = o;
    }
}

__global__ void fill_kernel(const int* __restrict__ eidx,
                            int* __restrict__ cursor,
                            int* __restrict__ list)
{
    const int i = blockIdx.x * blockDim.x + threadIdx.x;
    if (i < 2 * N_EDGES) {
        const int n   = eidx[i];
        const int pos = atomicAdd(&cursor[n], 1);
        list[pos] = (i < N_EDGES) ? i : i - N_EDGES;
    }
}

// ---------------------------------------------------------------------------
// Aggregation: one wave per node. SH=true reads the bf16 shadow.
// ---------------------------------------------------------------------------
template<bool SH>
__launch_bounds__(256)
__global__ void aggregate_kernel(const float* __restrict__ nef,
                                 const __bf16* __restrict__ sh,
                                 const int* __restrict__ offs,
                                 const int* __restrict__ list,
                                 float* __restrict__ edge_mean)
{
    const int lane   = threadIdx.x & 63;
    const int gwave  = (blockIdx.x * 256 + threadIdx.x) >> 6;
    const int nwaves = gridDim.x * 4;

    for (int n = gwave; n < N_NODES; n += nwaves) {
        const int beg = offs[n], end = offs[n + 1];
        float ax0 = 0.f, ay0 = 0.f, ax1 = 0.f, ay1 = 0.f;
        float ax2 = 0.f, ay2 = 0.f, ax3 = 0.f, ay3 = 0.f;
        int j = beg;
        if (SH) {
            const unsigned int* base = (const unsigned int*)sh;
            for (; j + 4 <= end; j += 4) {
                const int e0 = list[j], e1 = list[j + 1], e2 = list[j + 2], e3 = list[j + 3];
                const unsigned int u0 = base[(size_t)e0 * 64 + lane];
                const unsigned int u1 = base[(size_t)e1 * 64 + lane];
                const unsigned int u2 = base[(size_t)e2 * 64 + lane];
                const unsigned int u3 = base[(size_t)e3 * 64 + lane];
                ax0 += __uint_as_float(u0 << 16); ay0 += __uint_as_float(u0 & 0xffff0000u);
                ax1 += __uint_as_float(u1 << 16); ay1 += __uint_as_float(u1 & 0xffff0000u);
                ax2 += __uint_as_float(u2 << 16); ay2 += __uint_as_float(u2 & 0xffff0000u);
                ax3 += __uint_as_float(u3 << 16); ay3 += __uint_as_float(u3 & 0xffff0000u);
            }
            for (; j < end; ++j) {
                const unsigned int u = base[(size_t)list[j] * 64 + lane];
                ax0 += __uint_as_float(u << 16); ay0 += __uint_as_float(u & 0xffff0000u);
            }
        } else {
            for (; j + 4 <= end; j += 4) {
                const int e0 = list[j], e1 = list[j + 1], e2 = list[j + 2], e3 = list[j + 3];
                const float2 w0 = ((const float2*)(nef + (size_t)e0 * D))[lane];
                const float2 w1 = ((const float2*)(nef + (size_t)e1 * D))[lane];
                const float2 w2 = ((const float2*)(nef + (size_t)e2 * D))[lane];
                const float2 w3 = ((const float2*)(nef + (size_t)e3 * D))[lane];
                ax0 += w0.x; ay0 += w0.y; ax1 += w1.x; ay1 += w1.y;
                ax2 += w2.x; ay2 += w2.y; ax3 += w3.x; ay3 += w3.y;
            }
            for (; j < end; ++j) {
                const float2 w = ((const float2*)(nef + (size_t)list[j] * D))[lane];
                ax0 += w.x; ay0 += w.y;
            }
        }
        const float sx = (ax0 + ax1) + (ax2 + ax3);
        const float sy = (ay0 + ay1) + (ay2 + ay3);
        const float inv = 1.0f / ((float)(end - beg) + CNT_EPS);
        ((float2*)(edge_mean + (size_t)n * D))[lane] = make_float2(sx * inv, sy * inv);
    }
}

extern "C" void kernel_launch(void* const* d_in, const int* in_sizes, int n_in,
                              void* d_out, int out_size, void* d_ws, size_t ws_size,
                              hipStream_t stream) {
    const float* nodef   = (const float*)d_in[0];
    const float* edgef   = (const float*)d_in[1];
    const int*   eidx    = (const int*)d_in[2];
    const float* We      = (const float*)d_in[3];
    const float* be      = (const float*)d_in[4];
    const float* gamma_e = (const float*)d_in[5];
    const float* beta_e  = (const float*)d_in[6];
    const float* Wn      = (const float*)d_in[7];
    const float* bn      = (const float*)d_in[8];
    const float* gamma_n = (const float*)d_in[9];
    const float* beta_n  = (const float*)d_in[10];

    float* new_nodes = (float*)d_out;                      // also edge_mean buffer
    float* new_edges = (float*)d_out + (size_t)N_NODES * D;

    // workspace layout
    char* p = (char*)d_ws;
    __bf16* Wt  = (__bf16*)p;  p += 128 * 384 * 2;     // 98304
    __bf16* Wtn = (__bf16*)p;  p += 128 * 256 * 2;     // 65536
    int* cnt    = (int*)p;     p += (size_t)N_NODES * 4;
    int* excl   = (int*)p;     p += (size_t)N_NODES * 4;
    int* offs   = (int*)p;     p += (size_t)(N_NODES + 2) * 4;
    int* cursor = (int*)p;     p += (size_t)N_NODES * 4;
    int* bsum   = (int*)p;     p += 2048;
    int* list   = (int*)p;     p += (size_t)2 * N_EDGES * 4;
    const size_t base_bytes = (size_t)(p - (char*)d_ws);
    const size_t shadow_bytes = (size_t)N_EDGES * D * 2;
    __bf16* shadow = nullptr;
    if (ws_size >= base_bytes + shadow_bytes) shadow = (__bf16*)p;

    hipMemsetAsync(cnt, 0, (size_t)N_NODES * sizeof(int), stream);

    prep_w<<<320, 256, 0, stream>>>(We, Wn, Wt, Wtn);
    count_kernel<<<(2 * N_EDGES + 255) / 256, 256, 0, stream>>>(eidx, cnt);
    scan1<<<NB, 256, 0, stream>>>(cnt, excl, bsum);
    scan2<<<1, 256, 0, stream>>>(bsum, offs);
    scan3<<<NB, 256, 0, stream>>>(excl, bsum, offs, cursor);
    fill_kernel<<<(2 * N_EDGES + 255) / 256, 256, 0, stream>>>(eidx, cursor, list);

    edge_kernel<<<(N_EDGES + 255) / 256, 1024, 0, stream>>>(
        nodef, edgef, eidx, Wt, be, gamma_e, beta_e, new_edges, shadow);

    if (shadow)
        aggregate_kernel<true><<<2048, 256, 0, stream>>>(new_edges, shadow, offs, list, new_nodes);
    else
        aggregate_kernel<false><<<2048, 256, 0, stream>>>(new_edges, nullptr, offs, list, new_nodes);

    node_kernel<<<(N_NODES + 127) / 128, 256, 0, stream>>>(
        nodef, Wtn, bn, gamma_n, beta_n, new_nodes, new_nodes);
}

// Round 11
// 889.149 us; speedup vs baseline: 1.1749x; 1.1749x over previous
//
#include <hip/hip_runtime.h>

#define N_NODES 100000
#define N_EDGES 1000000
#define D 128
#define NB ((N_NODES + 255) / 256)   // 391 scan blocks
#define LN_EPS 1e-5f
#define CNT_EPS 1e-10f

typedef __bf16 bf16x8 __attribute__((ext_vector_type(8)));
typedef __bf16 bf16x4 __attribute__((ext_vector_type(4)));
typedef float  f32x4  __attribute__((ext_vector_type(4)));

#define ROWRED(v) { v += __shfl_xor(v, 1); v += __shfl_xor(v, 2); \
                    v += __shfl_xor(v, 4); v += __shfl_xor(v, 8); }

// ---------------------------------------------------------------------------
// Prep: Wt[j][k] = bf16(We[k][j] + (k==j))   (128x384, residual folded in)
//       Wtn[j][k] = bf16(Wn[k][j])           (128x256)
// ---------------------------------------------------------------------------
__global__ void prep_w(const float* __restrict__ We, const float* __restrict__ Wn,
                       __bf16* __restrict__ Wt, __bf16* __restrict__ Wtn)
{
    const int t = blockIdx.x * 256 + threadIdx.x;
    if (t < 128 * 384) {
        const int j = t / 384, k = t % 384;
        Wt[t] = (__bf16)(We[(size_t)k * 128 + j] + ((k == j) ? 1.0f : 0.0f));
    } else if (t < 128 * 384 + 128 * 256) {
        const int u = t - 128 * 384;
        const int j = u / 256, k = u % 256;
        Wtn[u] = (__bf16)Wn[(size_t)k * 128 + j];
    }
}

// ---------------------------------------------------------------------------
// Edge update via MFMA — the measured-best R2 structure (468 us):
// BM=128, 4 waves x (M=32,N=128), BK=32, single-buffer LDS, 2 barriers/K-step,
// compiler hoists next-tile loads over the MFMA burst.
// Changes vs R2 (both byte-savers, no structural change):
//   * residual folded into Wt -> no epilogue edgef re-read
//   * bf16 shadow of new_edges for the aggregate pass
// ---------------------------------------------------------------------------
#define ELOAD(kt) { \
    const float* ab = ((kt) < 4) ? edgp + (kt) * 32 \
                    : ((kt) < 8) ? srcp + ((kt) - 4) * 32 \
                                 : tgtp + ((kt) - 8) * 32; \
    v0 = ((const float4*)ab)[0]; v1 = ((const float4*)ab)[1]; \
    v2 = ((const float4*)ab)[2]; v3 = ((const float4*)ab)[3]; \
    wb0 = *(const bf16x8*)(wbp + (kt) * 32); \
    wb1 = *(const bf16x8*)(wbp + (kt) * 32 + 8); }

#define ESTORE() { \
    bf16x8 a0, a1; \
    a0[0] = (__bf16)v0.x; a0[1] = (__bf16)v0.y; a0[2] = (__bf16)v0.z; a0[3] = (__bf16)v0.w; \
    a0[4] = (__bf16)v1.x; a0[5] = (__bf16)v1.y; a0[6] = (__bf16)v1.z; a0[7] = (__bf16)v1.w; \
    a1[0] = (__bf16)v2.x; a1[1] = (__bf16)v2.y; a1[2] = (__bf16)v2.z; a1[3] = (__bf16)v2.w; \
    a1[4] = (__bf16)v3.x; a1[5] = (__bf16)v3.y; a1[6] = (__bf16)v3.z; a1[7] = (__bf16)v3.w; \
    *(bf16x8*)&As[lrow][lhalf * 16]     = a0; \
    *(bf16x8*)&As[lrow][lhalf * 16 + 8] = a1; \
    *(bf16x8*)&Bt[lrow][lhalf * 16]     = wb0; \
    *(bf16x8*)&Bt[lrow][lhalf * 16 + 8] = wb1; }

__launch_bounds__(256)
__global__ void edge_kernel(const float* __restrict__ nodef,
                            const float* __restrict__ edgef,
                            const int*   __restrict__ eidx,
                            const __bf16* __restrict__ Wt,
                            const float* __restrict__ be,
                            const float* __restrict__ gamma_e,
                            const float* __restrict__ beta_e,
                            float* __restrict__ new_edges,
                            __bf16* __restrict__ sh)
{
    __shared__ __bf16 As[128][40];   // [row][k], +8 pad
    __shared__ __bf16 Bt[128][40];   // [col][k]
    __shared__ int s_src[128], s_tgt[128];

    const int tid = threadIdx.x;
    const int e0  = blockIdx.x * 128;

    if (tid < 128) {
        s_src[tid] = eidx[min(e0 + tid, N_EDGES - 1)];
    } else {
        s_tgt[tid - 128] = eidx[N_EDGES + min(e0 + tid - 128, N_EDGES - 1)];
    }
    __syncthreads();

    const int lrow  = tid >> 1;
    const int lhalf = tid & 1;
    const size_t eclamp = (size_t)min(e0 + lrow, N_EDGES - 1);

    const float* edgp = edgef + eclamp * D + lhalf * 16;
    const float* srcp = nodef + (size_t)s_src[lrow] * D + lhalf * 16;
    const float* tgtp = nodef + (size_t)s_tgt[lrow] * D + lhalf * 16;
    const __bf16* wbp = Wt + (size_t)lrow * 384 + lhalf * 16;

    const int wid  = tid >> 6;
    const int lane = tid & 63;
    const int li   = lane & 15;
    const int lg   = lane >> 4;
    const int k0   = lg * 8;

    f32x4 acc[2][8];
    const f32x4 zero = {0.f, 0.f, 0.f, 0.f};
    #pragma unroll
    for (int m = 0; m < 2; ++m)
        #pragma unroll
        for (int n = 0; n < 8; ++n) acc[m][n] = zero;

    float4 v0, v1, v2, v3;
    bf16x8 wb0, wb1;

    #pragma unroll
    for (int kt = 0; kt < 12; ++kt) {
        ELOAD(kt);
        __syncthreads();   // previous tile fully consumed
        ESTORE();
        __syncthreads();   // tile ready

        const bf16x8 af0 = *(const bf16x8*)&As[wid * 32 + li][k0];
        const bf16x8 af1 = *(const bf16x8*)&As[wid * 32 + 16 + li][k0];
        #pragma unroll
        for (int nt = 0; nt < 8; ++nt) {
            const bf16x8 bfr = *(const bf16x8*)&Bt[nt * 16 + li][k0];
            acc[0][nt] = __builtin_amdgcn_mfma_f32_16x16x32_bf16(af0, bfr, acc[0][nt], 0, 0, 0);
            acc[1][nt] = __builtin_amdgcn_mfma_f32_16x16x32_bf16(af1, bfr, acc[1][nt], 0, 0, 0);
        }
    }

    // ---- epilogue: bias + LN + store (+ bf16 shadow); residual is in Wt ----
    float g[8], bt_[8], bias[8];
    #pragma unroll
    for (int nt = 0; nt < 8; ++nt) {
        const int col = nt * 16 + li;
        g[nt]    = gamma_e[col];
        bt_[nt]  = beta_e[col];
        bias[nt] = be[col];
    }

    #pragma unroll
    for (int mt = 0; mt < 2; ++mt) {
        #pragma unroll
        for (int r = 0; r < 4; ++r) {
            const int rl = wid * 32 + mt * 16 + lg * 4 + r;
            const int e  = e0 + rl;
            float x[8];
            float s = 0.f;
            #pragma unroll
            for (int nt = 0; nt < 8; ++nt) {
                x[nt] = acc[mt][nt][r] + bias[nt];
                s += x[nt];
            }
            ROWRED(s);
            const float mean = s * 0.0078125f;
            float vs = 0.f;
            #pragma unroll
            for (int nt = 0; nt < 8; ++nt) { const float d_ = x[nt] - mean; vs = fmaf(d_, d_, vs); }
            ROWRED(vs);
            const float rstd = rsqrtf(vs * 0.0078125f + LN_EPS);
            if (e < N_EDGES) {
                const size_t ec = (size_t)e;
                float y[8];
                #pragma unroll
                for (int nt = 0; nt < 8; ++nt)
                    y[nt] = fmaf((x[nt] - mean) * rstd, g[nt], bt_[nt]);
                #pragma unroll
                for (int nt = 0; nt < 8; ++nt)
                    new_edges[ec * D + nt * 16 + li] = y[nt];
                if (sh) {
                    #pragma unroll
                    for (int nt = 0; nt < 8; ++nt)
                        sh[ec * D + nt * 16 + li] = (__bf16)y[nt];
                }
            }
        }
    }
}

// ---------------------------------------------------------------------------
// Node update via MFMA (LDS 2-phase; only 782 blocks, not the bottleneck).
// ---------------------------------------------------------------------------
#define NSTORE() { \
    bf16x8 a0, a1; \
    a0[0] = (__bf16)v0.x; a0[1] = (__bf16)v0.y; a0[2] = (__bf16)v0.z; a0[3] = (__bf16)v0.w; \
    a0[4] = (__bf16)v1.x; a0[5] = (__bf16)v1.y; a0[6] = (__bf16)v1.z; a0[7] = (__bf16)v1.w; \
    a1[0] = (__bf16)v2.x; a1[1] = (__bf16)v2.y; a1[2] = (__bf16)v2.z; a1[3] = (__bf16)v2.w; \
    a1[4] = (__bf16)v3.x; a1[5] = (__bf16)v3.y; a1[6] = (__bf16)v3.z; a1[7] = (__bf16)v3.w; \
    *(bf16x8*)&NAs[lrow][lhalf * 16]     = a0; \
    *(bf16x8*)&NAs[lrow][lhalf * 16 + 8] = a1; \
    *(bf16x8*)&NBt[lrow][lhalf * 16]     = wb0; \
    *(bf16x8*)&NBt[lrow][lhalf * 16 + 8] = wb1; }

#define NLOAD(kt) { \
    const float* ab = ((kt) < 4) ? nodp + (kt) * 32 : aggp + ((kt) - 4) * 32; \
    v0 = ((const float4*)ab)[0]; v1 = ((const float4*)ab)[1]; \
    v2 = ((const float4*)ab)[2]; v3 = ((const float4*)ab)[3]; \
    wb0 = *(const bf16x8*)(wbp + (kt) * 32); \
    wb1 = *(const bf16x8*)(wbp + (kt) * 32 + 8); }

__launch_bounds__(256)
__global__ void node_kernel(const float* __restrict__ nodef,
                            const __bf16* __restrict__ Wtn,
                            const float* __restrict__ bn,
                            const float* __restrict__ gamma_n,
                            const float* __restrict__ beta_n,
                            const float* __restrict__ edge_mean,
                            float* __restrict__ new_nodes)
{
    __shared__ __bf16 NAs[128][40];
    __shared__ __bf16 NBt[128][40];

    const int tid = threadIdx.x;
    const int n0  = blockIdx.x * 128;

    const int lrow  = tid >> 1;
    const int lhalf = tid & 1;
    const size_t nclamp = (size_t)min(n0 + lrow, N_NODES - 1);

    const float* nodp = nodef     + nclamp * D + lhalf * 16;
    const float* aggp = edge_mean + nclamp * D + lhalf * 16;
    const __bf16* wbp = Wtn + (size_t)lrow * 256 + lhalf * 16;

    const int wid  = tid >> 6;
    const int lane = tid & 63;
    const int li   = lane & 15;
    const int lg   = lane >> 4;
    const int k0   = lg * 8;

    f32x4 acc[2][8];
    const f32x4 zero = {0.f, 0.f, 0.f, 0.f};
    #pragma unroll
    for (int m = 0; m < 2; ++m)
        #pragma unroll
        for (int n = 0; n < 8; ++n) acc[m][n] = zero;

    float4 v0, v1, v2, v3;
    bf16x8 wb0, wb1;

    #pragma unroll
    for (int kt = 0; kt < 8; ++kt) {
        NLOAD(kt);
        __syncthreads();
        NSTORE();
        __syncthreads();
        const bf16x8 af0 = *(const bf16x8*)&NAs[wid * 32 + li][k0];
        const bf16x8 af1 = *(const bf16x8*)&NAs[wid * 32 + 16 + li][k0];
        #pragma unroll
        for (int nt = 0; nt < 8; ++nt) {
            const bf16x8 bfr = *(const bf16x8*)&NBt[nt * 16 + li][k0];
            acc[0][nt] = __builtin_amdgcn_mfma_f32_16x16x32_bf16(af0, bfr, acc[0][nt], 0, 0, 0);
            acc[1][nt] = __builtin_amdgcn_mfma_f32_16x16x32_bf16(af1, bfr, acc[1][nt], 0, 0, 0);
        }
    }

    float g[8], bt_[8], bias[8];
    #pragma unroll
    for (int nt = 0; nt < 8; ++nt) {
        const int col = nt * 16 + li;
        g[nt]    = gamma_n[col];
        bt_[nt]  = beta_n[col];
        bias[nt] = bn[col];
    }

    #pragma unroll
    for (int mt = 0; mt < 2; ++mt) {
        #pragma unroll
        for (int r = 0; r < 4; ++r) {
            const int rl = wid * 32 + mt * 16 + lg * 4 + r;
            const int n  = n0 + rl;
            const size_t nc = (size_t)min(n, N_NODES - 1);
            float x[8];
            float s = 0.f;
            #pragma unroll
            for (int nt = 0; nt < 8; ++nt) {
                x[nt] = acc[mt][nt][r] + bias[nt] + nodef[nc * D + nt * 16 + li];
                s += x[nt];
            }
            ROWRED(s);
            const float mean = s * 0.0078125f;
            float vs = 0.f;
            #pragma unroll
            for (int nt = 0; nt < 8; ++nt) { const float d_ = x[nt] - mean; vs = fmaf(d_, d_, vs); }
            ROWRED(vs);
            const float rstd = rsqrtf(vs * 0.0078125f + LN_EPS);
            if (n < N_NODES) {
                #pragma unroll
                for (int nt = 0; nt < 8; ++nt)
                    new_nodes[nc * D + nt * 16 + li] =
                        fmaf((x[nt] - mean) * rstd, g[nt], bt_[nt]);
            }
        }
    }
}

// ---------------------------------------------------------------------------
// CSR build: count -> hierarchical scan -> fill
// ---------------------------------------------------------------------------
__global__ void count_kernel(const int* __restrict__ eidx, int* __restrict__ cnt)
{
    const int i = blockIdx.x * blockDim.x + threadIdx.x;
    if (i < 2 * N_EDGES) atomicAdd(&cnt[eidx[i]], 1);
}

__global__ void scan1(const int* __restrict__ cnt, int* __restrict__ excl,
                      int* __restrict__ bsum)
{
    const int tid = threadIdx.x, lane = tid & 63, wid = tid >> 6;
    const int i = blockIdx.x * 256 + tid;
    const int v = (i < N_NODES) ? cnt[i] : 0;
    int x = v;
    #pragma unroll
    for (int s = 1; s < 64; s <<= 1) { const int t = __shfl_up(x, s); if (lane >= s) x += t; }
    __shared__ int ws[4], wb[4];
    if (lane == 63) ws[wid] = x;
    __syncthreads();
    if (tid == 0) {
        int run = 0;
        #pragma unroll
        for (int w = 0; w < 4; ++w) { wb[w] = run; run += ws[w]; }
        bsum[blockIdx.x] = run;
    }
    __syncthreads();
    if (i < N_NODES) excl[i] = wb[wid] + x - v;
}

__global__ void scan2(int* __restrict__ bsum, int* __restrict__ offs)
{
    __shared__ int ws[4], wb[4];
    __shared__ int sbase;
    const int tid = threadIdx.x, lane = tid & 63, wid = tid >> 6;
    if (tid == 0) sbase = 0;
    __syncthreads();
    for (int chunk = 0; chunk < NB; chunk += 256) {
        const int i = chunk + tid;
        const int v = (i < NB) ? bsum[i] : 0;
        int x = v;
        #pragma unroll
        for (int s = 1; s < 64; s <<= 1) { const int t = __shfl_up(x, s); if (lane >= s) x += t; }
        if (lane == 63) ws[wid] = x;
        __syncthreads();
        if (tid == 0) {
            int run = sbase;
            #pragma unroll
            for (int w = 0; w < 4; ++w) { wb[w] = run; run += ws[w]; }
            sbase = run;
        }
        __syncthreads();
        if (i < NB) bsum[i] = wb[wid] + x - v;
        __syncthreads();
    }
    if (tid == 0) offs[N_NODES] = sbase;
}

__global__ void scan3(const int* __restrict__ excl, const int* __restrict__ bsum,
                      int* __restrict__ offs, int* __restrict__ cursor)
{
    const int i = blockIdx.x * 256 + threadIdx.x;
    if (i < N_NODES) {
        const int o = excl[i] + bsum[i >> 8];
        offs[i] = o;
        cursor[i] = o;
    }
}

__global__ void fill_kernel(const int* __restrict__ eidx,
                            int* __restrict__ cursor,
                            int* __restrict__ list)
{
    const int i = blockIdx.x * blockDim.x + threadIdx.x;
    if (i < 2 * N_EDGES) {
        const int n   = eidx[i];
        const int pos = atomicAdd(&cursor[n], 1);
        list[pos] = (i < N_EDGES) ? i : i - N_EDGES;
    }
}

// ---------------------------------------------------------------------------
// Aggregation: one wave per node, unroll-8 (MLP=8). SH=true reads bf16 shadow.
// ---------------------------------------------------------------------------
template<bool SH>
__launch_bounds__(256)
__global__ void aggregate_kernel(const float* __restrict__ nef,
                                 const __bf16* __restrict__ sh,
                                 const int* __restrict__ offs,
                                 const int* __restrict__ list,
                                 float* __restrict__ edge_mean)
{
    const int lane   = threadIdx.x & 63;
    const int gwave  = (blockIdx.x * 256 + threadIdx.x) >> 6;
    const int nwaves = gridDim.x * 4;

    for (int n = gwave; n < N_NODES; n += nwaves) {
        const int beg = offs[n], end = offs[n + 1];
        float ax0 = 0.f, ay0 = 0.f, ax1 = 0.f, ay1 = 0.f;
        float ax2 = 0.f, ay2 = 0.f, ax3 = 0.f, ay3 = 0.f;
        int j = beg;
        if (SH) {
            const unsigned int* base = (const unsigned int*)sh;
            for (; j + 8 <= end; j += 8) {
                unsigned int u[8];
                #pragma unroll
                for (int q = 0; q < 8; ++q)
                    u[q] = base[(size_t)list[j + q] * 64 + lane];
                ax0 += __uint_as_float(u[0] << 16) + __uint_as_float(u[4] << 16);
                ay0 += __uint_as_float(u[0] & 0xffff0000u) + __uint_as_float(u[4] & 0xffff0000u);
                ax1 += __uint_as_float(u[1] << 16) + __uint_as_float(u[5] << 16);
                ay1 += __uint_as_float(u[1] & 0xffff0000u) + __uint_as_float(u[5] & 0xffff0000u);
                ax2 += __uint_as_float(u[2] << 16) + __uint_as_float(u[6] << 16);
                ay2 += __uint_as_float(u[2] & 0xffff0000u) + __uint_as_float(u[6] & 0xffff0000u);
                ax3 += __uint_as_float(u[3] << 16) + __uint_as_float(u[7] << 16);
                ay3 += __uint_as_float(u[3] & 0xffff0000u) + __uint_as_float(u[7] & 0xffff0000u);
            }
            for (; j < end; ++j) {
                const unsigned int u = base[(size_t)list[j] * 64 + lane];
                ax0 += __uint_as_float(u << 16); ay0 += __uint_as_float(u & 0xffff0000u);
            }
        } else {
            for (; j + 4 <= end; j += 4) {
                const int e0 = list[j], e1 = list[j + 1], e2 = list[j + 2], e3 = list[j + 3];
                const float2 w0 = ((const float2*)(nef + (size_t)e0 * D))[lane];
                const float2 w1 = ((const float2*)(nef + (size_t)e1 * D))[lane];
                const float2 w2 = ((const float2*)(nef + (size_t)e2 * D))[lane];
                const float2 w3 = ((const float2*)(nef + (size_t)e3 * D))[lane];
                ax0 += w0.x; ay0 += w0.y; ax1 += w1.x; ay1 += w1.y;
                ax2 += w2.x; ay2 += w2.y; ax3 += w3.x; ay3 += w3.y;
            }
            for (; j < end; ++j) {
                const float2 w = ((const float2*)(nef + (size_t)list[j] * D))[lane];
                ax0 += w.x; ay0 += w.y;
            }
        }
        const float sx = (ax0 + ax1) + (ax2 + ax3);
        const float sy = (ay0 + ay1) + (ay2 + ay3);
        const float inv = 1.0f / ((float)(end - beg) + CNT_EPS);
        ((float2*)(edge_mean + (size_t)n * D))[lane] = make_float2(sx * inv, sy * inv);
    }
}

extern "C" void kernel_launch(void* const* d_in, const int* in_sizes, int n_in,
                              void* d_out, int out_size, void* d_ws, size_t ws_size,
                              hipStream_t stream) {
    const float* nodef   = (const float*)d_in[0];
    const float* edgef   = (const float*)d_in[1];
    const int*   eidx    = (const int*)d_in[2];
    const float* We      = (const float*)d_in[3];
    const float* be      = (const float*)d_in[4];
    const float* gamma_e = (const float*)d_in[5];
    const float* beta_e  = (const float*)d_in[6];
    const float* Wn      = (const float*)d_in[7];
    const float* bn      = (const float*)d_in[8];
    const float* gamma_n = (const float*)d_in[9];
    const float* beta_n  = (const float*)d_in[10];

    float* new_nodes = (float*)d_out;                      // also edge_mean buffer
    float* new_edges = (float*)d_out + (size_t)N_NODES * D;

    // workspace layout
    char* p = (char*)d_ws;
    __bf16* Wt  = (__bf16*)p;  p += 128 * 384 * 2;     // 98304
    __bf16* Wtn = (__bf16*)p;  p += 128 * 256 * 2;     // 65536
    int* cnt    = (int*)p;     p += (size_t)N_NODES * 4;
    int* excl   = (int*)p;     p += (size_t)N_NODES * 4;
    int* offs   = (int*)p;     p += (size_t)(N_NODES + 2) * 4;
    int* cursor = (int*)p;     p += (size_t)N_NODES * 4;
    int* bsum   = (int*)p;     p += 2048;
    int* list   = (int*)p;     p += (size_t)2 * N_EDGES * 4;
    const size_t base_bytes = (size_t)(p - (char*)d_ws);
    const size_t shadow_bytes = (size_t)N_EDGES * D * 2;
    __bf16* shadow = nullptr;
    if (ws_size >= base_bytes + shadow_bytes) shadow = (__bf16*)p;

    hipMemsetAsync(cnt, 0, (size_t)N_NODES * sizeof(int), stream);

    prep_w<<<320, 256, 0, stream>>>(We, Wn, Wt, Wtn);
    count_kernel<<<(2 * N_EDGES + 255) / 256, 256, 0, stream>>>(eidx, cnt);
    scan1<<<NB, 256, 0, stream>>>(cnt, excl, bsum);
    scan2<<<1, 256, 0, stream>>>(bsum, offs);
    scan3<<<NB, 256, 0, stream>>>(excl, bsum, offs, cursor);
    fill_kernel<<<(2 * N_EDGES + 255) / 256, 256, 0, stream>>>(eidx, cursor, list);

    edge_kernel<<<(N_EDGES + 127) / 128, 256, 0, stream>>>(
        nodef, edgef, eidx, Wt, be, gamma_e, beta_e, new_edges, shadow);

    if (shadow)
        aggregate_kernel<true><<<2048, 256, 0, stream>>>(new_edges, shadow, offs, list, new_nodes);
    else
        aggregate_kernel<false><<<2048, 256, 0, stream>>>(new_edges, nullptr, offs, list, new_nodes);

    node_kernel<<<(N_NODES + 127) / 128, 256, 0, stream>>>(
        nodef, Wtn, bn, gamma_n, beta_n, new_nodes, new_nodes);
}

// Round 12
// 832.169 us; speedup vs baseline: 1.2553x; 1.0685x over previous
//
#include <hip/hip_runtime.h>

#define N_NODES 100000
#define N_EDGES 1000000
#define D 128
#define NB ((N_NODES + 255) / 256)   // 391 scan blocks
#define LN_EPS 1e-5f
#define CNT_EPS 1e-10f

typedef __bf16 bf16x8 __attribute__((ext_vector_type(8)));
typedef __bf16 bf16x4 __attribute__((ext_vector_type(4)));
typedef float  f32x4  __attribute__((ext_vector_type(4)));

#define ROWRED(v) { v += __shfl_xor(v, 1); v += __shfl_xor(v, 2); \
                    v += __shfl_xor(v, 4); v += __shfl_xor(v, 8); }

// async 16B global->LDS; LDS dest is wave-uniform base + lane*16 (m104/m108)
#define GLOAD16(g, l) \
    __builtin_amdgcn_global_load_lds( \
        (const __attribute__((address_space(1))) void*)(g), \
        (__attribute__((address_space(3))) void*)(l), 16, 0, 0)

// ---------------------------------------------------------------------------
// Prep: Wt[j][k] = bf16(We[k][j] + (k==j))   (128x384, residual folded in)
//       Wtn[j][k] = bf16(Wn[k][j])           (128x256)
// ---------------------------------------------------------------------------
__global__ void prep_w(const float* __restrict__ We, const float* __restrict__ Wn,
                       __bf16* __restrict__ Wt, __bf16* __restrict__ Wtn)
{
    const int t = blockIdx.x * 256 + threadIdx.x;
    if (t < 128 * 384) {
        const int j = t / 384, k = t % 384;
        Wt[t] = (__bf16)(We[(size_t)k * 128 + j] + ((k == j) ? 1.0f : 0.0f));
    } else if (t < 128 * 384 + 128 * 256) {
        const int u = t - 128 * 384;
        const int j = u / 256, k = u % 256;
        Wtn[u] = (__bf16)Wn[(size_t)k * 128 + j];
    }
}

// ---------------------------------------------------------------------------
// Edge update via MFMA, async-staged (m97 pattern):
//  - A tile kept f32 in LDS [2][128][32] (32KB), B bf16 [2][128][32] (16KB)
//  - ALL staging via global_load_lds w=16: linear LDS dest, XOR-pre-swizzled
//    global source; fragment reads apply the same XOR (rule #21).
//      A: chunk(16B) ^ (row&7)   -> <=2-way on ds_read_b128
//      B: chunk(16B) ^ ((col>>1)&3)
//  - double buffer, ONE __syncthreads per K-step (loads overlap MFMA phase)
//  - residual folded into Wt; epilogue = bias + LN + f32 & bf16-shadow store
// ---------------------------------------------------------------------------
#define ESTAGE(b, kt) { \
    _Pragma("unroll") \
    for (int r = 0; r < 4; ++r) { \
        const float* g = ((kt) < 4) ? baseE[r] + (kt) * 32 \
                       : ((kt) < 8) ? baseS[r] + ((kt) - 4) * 32 \
                                    : baseT[r] + ((kt) - 8) * 32; \
        GLOAD16(g, &Asf[b][(wid * 4 + r) * 256]); \
    } \
    _Pragma("unroll") \
    for (int r = 0; r < 2; ++r) \
        GLOAD16(baseW[r] + (kt) * 32, &Btf[b][(wid * 2 + r) * 512]); }

#define EFRAG_MFMA(b) { \
    bf16x8 afm[2]; \
    _Pragma("unroll") \
    for (int mt = 0; mt < 2; ++mt) { \
        const int row = wid * 32 + mt * 16 + li; \
        const int swz = li & 7; \
        const f32x4 va = *(const f32x4*)&Asf[b][row * 32 + (((lg * 2) ^ swz) << 2)]; \
        const f32x4 vb = *(const f32x4*)&Asf[b][row * 32 + (((lg * 2 + 1) ^ swz) << 2)]; \
        bf16x8 af; \
        af[0] = (__bf16)va[0]; af[1] = (__bf16)va[1]; \
        af[2] = (__bf16)va[2]; af[3] = (__bf16)va[3]; \
        af[4] = (__bf16)vb[0]; af[5] = (__bf16)vb[1]; \
        af[6] = (__bf16)vb[2]; af[7] = (__bf16)vb[3]; \
        afm[mt] = af; \
    } \
    _Pragma("unroll") \
    for (int nt = 0; nt < 8; ++nt) { \
        const int col = nt * 16 + li; \
        const bf16x8 bfr = \
            *(const bf16x8*)&Btf[b][col * 32 + ((lg ^ ((li >> 1) & 3)) << 3)]; \
        acc[0][nt] = __builtin_amdgcn_mfma_f32_16x16x32_bf16(afm[0], bfr, acc[0][nt], 0, 0, 0); \
        acc[1][nt] = __builtin_amdgcn_mfma_f32_16x16x32_bf16(afm[1], bfr, acc[1][nt], 0, 0, 0); \
    } }

__launch_bounds__(256)
__global__ void edge_kernel(const float* __restrict__ nodef,
                            const float* __restrict__ edgef,
                            const int*   __restrict__ eidx,
                            const __bf16* __restrict__ Wt,
                            const float* __restrict__ be,
                            const float* __restrict__ gamma_e,
                            const float* __restrict__ beta_e,
                            float* __restrict__ new_edges,
                            __bf16* __restrict__ sh)
{
    __shared__ float  Asf[2][4096];   // [buf][row*32 + chunk-swizzled k] f32
    __shared__ __bf16 Btf[2][4096];   // [buf][col*32 + chunk-swizzled k] bf16
    __shared__ int s_src[128], s_tgt[128];

    const int tid = threadIdx.x;
    const int e0  = blockIdx.x * 128;

    if (tid < 128) {
        s_src[tid] = eidx[min(e0 + tid, N_EDGES - 1)];
    } else {
        s_tgt[tid - 128] = eidx[N_EDGES + min(e0 + tid - 128, N_EDGES - 1)];
    }
    __syncthreads();

    const int wid  = tid >> 6;
    const int lane = tid & 63;
    const int li   = lane & 15;
    const int lg   = lane >> 4;

    // per-thread pre-swizzled global base pointers (kt-independent)
    const float* baseE[4];
    const float* baseS[4];
    const float* baseT[4];
    #pragma unroll
    for (int r = 0; r < 4; ++r) {
        const int idx = (wid * 4 + r) * 64 + lane;    // flat 16B-chunk id
        const int row = idx >> 3;
        const int ch  = idx & 7;
        const int cg  = ch ^ (row & 7);
        const int er  = min(e0 + row, N_EDGES - 1);
        baseE[r] = edgef + (size_t)er * D + cg * 4;
        baseS[r] = nodef + (size_t)s_src[row] * D + cg * 4;
        baseT[r] = nodef + (size_t)s_tgt[row] * D + cg * 4;
    }
    const __bf16* baseW[2];
    #pragma unroll
    for (int r = 0; r < 2; ++r) {
        const int idx = (wid * 2 + r) * 64 + lane;
        const int col = idx >> 2;
        const int ch  = idx & 3;
        const int cg  = ch ^ ((col >> 1) & 3);
        baseW[r] = Wt + (size_t)col * 384 + cg * 8;
    }

    f32x4 acc[2][8];
    const f32x4 zero = {0.f, 0.f, 0.f, 0.f};
    #pragma unroll
    for (int m = 0; m < 2; ++m)
        #pragma unroll
        for (int n = 0; n < 8; ++n) acc[m][n] = zero;

    ESTAGE(0, 0);
    __syncthreads();                      // drain prologue loads
    #pragma unroll
    for (int kt = 0; kt < 12; ++kt) {
        const int b = kt & 1;
        if (kt < 11) ESTAGE(b ^ 1, kt + 1);   // async, in flight over MFMAs
        EFRAG_MFMA(b);
        if (kt < 11) __syncthreads();         // drains next-tile loads too
    }

    // ---- epilogue: bias + LN + store (+ bf16 shadow); residual is in Wt ----
    float g[8], bt_[8], bias[8];
    #pragma unroll
    for (int nt = 0; nt < 8; ++nt) {
        const int col = nt * 16 + li;
        g[nt]    = gamma_e[col];
        bt_[nt]  = beta_e[col];
        bias[nt] = be[col];
    }

    #pragma unroll
    for (int mt = 0; mt < 2; ++mt) {
        #pragma unroll
        for (int r = 0; r < 4; ++r) {
            const int rl = wid * 32 + mt * 16 + lg * 4 + r;
            const int e  = e0 + rl;
            float x[8];
            float s = 0.f;
            #pragma unroll
            for (int nt = 0; nt < 8; ++nt) {
                x[nt] = acc[mt][nt][r] + bias[nt];
                s += x[nt];
            }
            ROWRED(s);
            const float mean = s * 0.0078125f;
            float vs = 0.f;
            #pragma unroll
            for (int nt = 0; nt < 8; ++nt) { const float d_ = x[nt] - mean; vs = fmaf(d_, d_, vs); }
            ROWRED(vs);
            const float rstd = rsqrtf(vs * 0.0078125f + LN_EPS);
            if (e < N_EDGES) {
                const size_t ec = (size_t)e;
                float y[8];
                #pragma unroll
                for (int nt = 0; nt < 8; ++nt)
                    y[nt] = fmaf((x[nt] - mean) * rstd, g[nt], bt_[nt]);
                #pragma unroll
                for (int nt = 0; nt < 8; ++nt)
                    new_edges[ec * D + nt * 16 + li] = y[nt];
                if (sh) {
                    #pragma unroll
                    for (int nt = 0; nt < 8; ++nt)
                        sh[ec * D + nt * 16 + li] = (__bf16)y[nt];
                }
            }
        }
    }
}

// ---------------------------------------------------------------------------
// Node update via MFMA (unchanged R10; not the bottleneck).
// ---------------------------------------------------------------------------
#define NSTORE() { \
    bf16x8 a0, a1; \
    a0[0] = (__bf16)v0.x; a0[1] = (__bf16)v0.y; a0[2] = (__bf16)v0.z; a0[3] = (__bf16)v0.w; \
    a0[4] = (__bf16)v1.x; a0[5] = (__bf16)v1.y; a0[6] = (__bf16)v1.z; a0[7] = (__bf16)v1.w; \
    a1[0] = (__bf16)v2.x; a1[1] = (__bf16)v2.y; a1[2] = (__bf16)v2.z; a1[3] = (__bf16)v2.w; \
    a1[4] = (__bf16)v3.x; a1[5] = (__bf16)v3.y; a1[6] = (__bf16)v3.z; a1[7] = (__bf16)v3.w; \
    *(bf16x8*)&NAs[lrow][lhalf * 16]     = a0; \
    *(bf16x8*)&NAs[lrow][lhalf * 16 + 8] = a1; \
    *(bf16x8*)&NBt[lrow][lhalf * 16]     = wb0; \
    *(bf16x8*)&NBt[lrow][lhalf * 16 + 8] = wb1; }

#define NLOAD(kt) { \
    const float* ab = ((kt) < 4) ? nodp + (kt) * 32 : aggp + ((kt) - 4) * 32; \
    v0 = ((const float4*)ab)[0]; v1 = ((const float4*)ab)[1]; \
    v2 = ((const float4*)ab)[2]; v3 = ((const float4*)ab)[3]; \
    wb0 = *(const bf16x8*)(wbp + (kt) * 32); \
    wb1 = *(const bf16x8*)(wbp + (kt) * 32 + 8); }

__launch_bounds__(256)
__global__ void node_kernel(const float* __restrict__ nodef,
                            const __bf16* __restrict__ Wtn,
                            const float* __restrict__ bn,
                            const float* __restrict__ gamma_n,
                            const float* __restrict__ beta_n,
                            const float* __restrict__ edge_mean,
                            float* __restrict__ new_nodes)
{
    __shared__ __bf16 NAs[128][40];
    __shared__ __bf16 NBt[128][40];

    const int tid = threadIdx.x;
    const int n0  = blockIdx.x * 128;

    const int lrow  = tid >> 1;
    const int lhalf = tid & 1;
    const size_t nclamp = (size_t)min(n0 + lrow, N_NODES - 1);

    const float* nodp = nodef     + nclamp * D + lhalf * 16;
    const float* aggp = edge_mean + nclamp * D + lhalf * 16;
    const __bf16* wbp = Wtn + (size_t)lrow * 256 + lhalf * 16;

    const int wid  = tid >> 6;
    const int lane = tid & 63;
    const int li   = lane & 15;
    const int lg   = lane >> 4;
    const int k0   = lg * 8;

    f32x4 acc[2][8];
    const f32x4 zero = {0.f, 0.f, 0.f, 0.f};
    #pragma unroll
    for (int m = 0; m < 2; ++m)
        #pragma unroll
        for (int n = 0; n < 8; ++n) acc[m][n] = zero;

    float4 v0, v1, v2, v3;
    bf16x8 wb0, wb1;

    #pragma unroll
    for (int kt = 0; kt < 8; ++kt) {
        NLOAD(kt);
        __syncthreads();
        NSTORE();
        __syncthreads();
        const bf16x8 af0 = *(const bf16x8*)&NAs[wid * 32 + li][k0];
        const bf16x8 af1 = *(const bf16x8*)&NAs[wid * 32 + 16 + li][k0];
        #pragma unroll
        for (int nt = 0; nt < 8; ++nt) {
            const bf16x8 bfr = *(const bf16x8*)&NBt[nt * 16 + li][k0];
            acc[0][nt] = __builtin_amdgcn_mfma_f32_16x16x32_bf16(af0, bfr, acc[0][nt], 0, 0, 0);
            acc[1][nt] = __builtin_amdgcn_mfma_f32_16x16x32_bf16(af1, bfr, acc[1][nt], 0, 0, 0);
        }
    }

    float g[8], bt_[8], bias[8];
    #pragma unroll
    for (int nt = 0; nt < 8; ++nt) {
        const int col = nt * 16 + li;
        g[nt]    = gamma_n[col];
        bt_[nt]  = beta_n[col];
        bias[nt] = bn[col];
    }

    #pragma unroll
    for (int mt = 0; mt < 2; ++mt) {
        #pragma unroll
        for (int r = 0; r < 4; ++r) {
            const int rl = wid * 32 + mt * 16 + lg * 4 + r;
            const int n  = n0 + rl;
            const size_t nc = (size_t)min(n, N_NODES - 1);
            float x[8];
            float s = 0.f;
            #pragma unroll
            for (int nt = 0; nt < 8; ++nt) {
                x[nt] = acc[mt][nt][r] + bias[nt] + nodef[nc * D + nt * 16 + li];
                s += x[nt];
            }
            ROWRED(s);
            const float mean = s * 0.0078125f;
            float vs = 0.f;
            #pragma unroll
            for (int nt = 0; nt < 8; ++nt) { const float d_ = x[nt] - mean; vs = fmaf(d_, d_, vs); }
            ROWRED(vs);
            const float rstd = rsqrtf(vs * 0.0078125f + LN_EPS);
            if (n < N_NODES) {
                #pragma unroll
                for (int nt = 0; nt < 8; ++nt)
                    new_nodes[nc * D + nt * 16 + li] =
                        fmaf((x[nt] - mean) * rstd, g[nt], bt_[nt]);
            }
        }
    }
}

// ---------------------------------------------------------------------------
// CSR build: count -> hierarchical scan -> fill
// ---------------------------------------------------------------------------
__global__ void count_kernel(const int* __restrict__ eidx, int* __restrict__ cnt)
{
    const int i = blockIdx.x * blockDim.x + threadIdx.x;
    if (i < 2 * N_EDGES) atomicAdd(&cnt[eidx[i]], 1);
}

__global__ void scan1(const int* __restrict__ cnt, int* __restrict__ excl,
                      int* __restrict__ bsum)
{
    const int tid = threadIdx.x, lane = tid & 63, wid = tid >> 6;
    const int i = blockIdx.x * 256 + tid;
    const int v = (i < N_NODES) ? cnt[i] : 0;
    int x = v;
    #pragma unroll
    for (int s = 1; s < 64; s <<= 1) { const int t = __shfl_up(x, s); if (lane >= s) x += t; }
    __shared__ int ws[4], wb[4];
    if (lane == 63) ws[wid] = x;
    __syncthreads();
    if (tid == 0) {
        int run = 0;
        #pragma unroll
        for (int w = 0; w < 4; ++w) { wb[w] = run; run += ws[w]; }
        bsum[blockIdx.x] = run;
    }
    __syncthreads();
    if (i < N_NODES) excl[i] = wb[wid] + x - v;
}

__global__ void scan2(int* __restrict__ bsum, int* __restrict__ offs)
{
    __shared__ int ws[4], wb[4];
    __shared__ int sbase;
    const int tid = threadIdx.x, lane = tid & 63, wid = tid >> 6;
    if (tid == 0) sbase = 0;
    __syncthreads();
    for (int chunk = 0; chunk < NB; chunk += 256) {
        const int i = chunk + tid;
        const int v = (i < NB) ? bsum[i] : 0;
        int x = v;
        #pragma unroll
        for (int s = 1; s < 64; s <<= 1) { const int t = __shfl_up(x, s); if (lane >= s) x += t; }
        if (lane == 63) ws[wid] = x;
        __syncthreads();
        if (tid == 0) {
            int run = sbase;
            #pragma unroll
            for (int w = 0; w < 4; ++w) { wb[w] = run; run += ws[w]; }
            sbase = run;
        }
        __syncthreads();
        if (i < NB) bsum[i] = wb[wid] + x - v;
        __syncthreads();
    }
    if (tid == 0) offs[N_NODES] = sbase;
}

__global__ void scan3(const int* __restrict__ excl, const int* __restrict__ bsum,
                      int* __restrict__ offs, int* __restrict__ cursor)
{
    const int i = blockIdx.x * 256 + threadIdx.x;
    if (i < N_NODES) {
        const int o = excl[i] + bsum[i >> 8];
        offs[i] = o;
        cursor[i] = o;
    }
}

__global__ void fill_kernel(const int* __restrict__ eidx,
                            int* __restrict__ cursor,
                            int* __restrict__ list)
{
    const int i = blockIdx.x * blockDim.x + threadIdx.x;
    if (i < 2 * N_EDGES) {
        const int n   = eidx[i];
        const int pos = atomicAdd(&cursor[n], 1);
        list[pos] = (i < N_EDGES) ? i : i - N_EDGES;
    }
}

// ---------------------------------------------------------------------------
// Aggregation: one wave per node, unroll-8 (MLP=8). SH=true reads bf16 shadow.
// ---------------------------------------------------------------------------
template<bool SH>
__launch_bounds__(256)
__global__ void aggregate_kernel(const float* __restrict__ nef,
                                 const __bf16* __restrict__ sh,
                                 const int* __restrict__ offs,
                                 const int* __restrict__ list,
                                 float* __restrict__ edge_mean)
{
    const int lane   = threadIdx.x & 63;
    const int gwave  = (blockIdx.x * 256 + threadIdx.x) >> 6;
    const int nwaves = gridDim.x * 4;

    for (int n = gwave; n < N_NODES; n += nwaves) {
        const int beg = offs[n], end = offs[n + 1];
        float ax0 = 0.f, ay0 = 0.f, ax1 = 0.f, ay1 = 0.f;
        float ax2 = 0.f, ay2 = 0.f, ax3 = 0.f, ay3 = 0.f;
        int j = beg;
        if (SH) {
            const unsigned int* base = (const unsigned int*)sh;
            for (; j + 8 <= end; j += 8) {
                unsigned int u[8];
                #pragma unroll
                for (int q = 0; q < 8; ++q)
                    u[q] = base[(size_t)list[j + q] * 64 + lane];
                ax0 += __uint_as_float(u[0] << 16) + __uint_as_float(u[4] << 16);
                ay0 += __uint_as_float(u[0] & 0xffff0000u) + __uint_as_float(u[4] & 0xffff0000u);
                ax1 += __uint_as_float(u[1] << 16) + __uint_as_float(u[5] << 16);
                ay1 += __uint_as_float(u[1] & 0xffff0000u) + __uint_as_float(u[5] & 0xffff0000u);
                ax2 += __uint_as_float(u[2] << 16) + __uint_as_float(u[6] << 16);
                ay2 += __uint_as_float(u[2] & 0xffff0000u) + __uint_as_float(u[6] & 0xffff0000u);
                ax3 += __uint_as_float(u[3] << 16) + __uint_as_float(u[7] << 16);
                ay3 += __uint_as_float(u[3] & 0xffff0000u) + __uint_as_float(u[7] & 0xffff0000u);
            }
            for (; j < end; ++j) {
                const unsigned int u = base[(size_t)list[j] * 64 + lane];
                ax0 += __uint_as_float(u << 16); ay0 += __uint_as_float(u & 0xffff0000u);
            }
        } else {
            for (; j + 4 <= end; j += 4) {
                const int e0 = list[j], e1 = list[j + 1], e2 = list[j + 2], e3 = list[j + 3];
                const float2 w0 = ((const float2*)(nef + (size_t)e0 * D))[lane];
                const float2 w1 = ((const float2*)(nef + (size_t)e1 * D))[lane];
                const float2 w2 = ((const float2*)(nef + (size_t)e2 * D))[lane];
                const float2 w3 = ((const float2*)(nef + (size_t)e3 * D))[lane];
                ax0 += w0.x; ay0 += w0.y; ax1 += w1.x; ay1 += w1.y;
                ax2 += w2.x; ay2 += w2.y; ax3 += w3.x; ay3 += w3.y;
            }
            for (; j < end; ++j) {
                const float2 w = ((const float2*)(nef + (size_t)list[j] * D))[lane];
                ax0 += w.x; ay0 += w.y;
            }
        }
        const float sx = (ax0 + ax1) + (ax2 + ax3);
        const float sy = (ay0 + ay1) + (ay2 + ay3);
        const float inv = 1.0f / ((float)(end - beg) + CNT_EPS);
        ((float2*)(edge_mean + (size_t)n * D))[lane] = make_float2(sx * inv, sy * inv);
    }
}

extern "C" void kernel_launch(void* const* d_in, const int* in_sizes, int n_in,
                              void* d_out, int out_size, void* d_ws, size_t ws_size,
                              hipStream_t stream) {
    const float* nodef   = (const float*)d_in[0];
    const float* edgef   = (const float*)d_in[1];
    const int*   eidx    = (const int*)d_in[2];
    const float* We      = (const float*)d_in[3];
    const float* be      = (const float*)d_in[4];
    const float* gamma_e = (const float*)d_in[5];
    const float* beta_e  = (const float*)d_in[6];
    const float* Wn      = (const float*)d_in[7];
    const float* bn      = (const float*)d_in[8];
    const float* gamma_n = (const float*)d_in[9];
    const float* beta_n  = (const float*)d_in[10];

    float* new_nodes = (float*)d_out;                      // also edge_mean buffer
    float* new_edges = (float*)d_out + (size_t)N_NODES * D;

    // workspace layout
    char* p = (char*)d_ws;
    __bf16* Wt  = (__bf16*)p;  p += 128 * 384 * 2;     // 98304
    __bf16* Wtn = (__bf16*)p;  p += 128 * 256 * 2;     // 65536
    int* cnt    = (int*)p;     p += (size_t)N_NODES * 4;
    int* excl   = (int*)p;     p += (size_t)N_NODES * 4;
    int* offs   = (int*)p;     p += (size_t)(N_NODES + 2) * 4;
    int* cursor = (int*)p;     p += (size_t)N_NODES * 4;
    int* bsum   = (int*)p;     p += 2048;
    int* list   = (int*)p;     p += (size_t)2 * N_EDGES * 4;
    const size_t base_bytes = (size_t)(p - (char*)d_ws);
    const size_t shadow_bytes = (size_t)N_EDGES * D * 2;
    __bf16* shadow = nullptr;
    if (ws_size >= base_bytes + shadow_bytes) shadow = (__bf16*)p;

    hipMemsetAsync(cnt, 0, (size_t)N_NODES * sizeof(int), stream);

    prep_w<<<320, 256, 0, stream>>>(We, Wn, Wt, Wtn);
    count_kernel<<<(2 * N_EDGES + 255) / 256, 256, 0, stream>>>(eidx, cnt);
    scan1<<<NB, 256, 0, stream>>>(cnt, excl, bsum);
    scan2<<<1, 256, 0, stream>>>(bsum, offs);
    scan3<<<NB, 256, 0, stream>>>(excl, bsum, offs, cursor);
    fill_kernel<<<(2 * N_EDGES + 255) / 256, 256, 0, stream>>>(eidx, cursor, list);

    edge_kernel<<<(N_EDGES + 127) / 128, 256, 0, stream>>>(
        nodef, edgef, eidx, Wt, be, gamma_e, beta_e, new_edges, shadow);

    if (shadow)
        aggregate_kernel<true><<<2048, 256, 0, stream>>>(new_edges, shadow, offs, list, new_nodes);
    else
        aggregate_kernel<false><<<2048, 256, 0, stream>>>(new_edges, nullptr, offs, list, new_nodes);

    node_kernel<<<(N_NODES + 127) / 128, 256, 0, stream>>>(
        nodef, Wtn, bn, gamma_n, beta_n, new_nodes, new_nodes);
}

// Round 13
// 819.067 us; speedup vs baseline: 1.2754x; 1.0160x over previous
//
#include <hip/hip_runtime.h>

#define N_NODES 100000
#define N_EDGES 1000000
#define D 128
#define NB ((N_NODES + 255) / 256)   // 391 scan blocks
#define LN_EPS 1e-5f
#define CNT_EPS 1e-10f

typedef __bf16 bf16x8 __attribute__((ext_vector_type(8)));
typedef __bf16 bf16x4 __attribute__((ext_vector_type(4)));
typedef float  f32x4  __attribute__((ext_vector_type(4)));

#define ROWRED(v) { v += __shfl_xor(v, 1); v += __shfl_xor(v, 2); \
                    v += __shfl_xor(v, 4); v += __shfl_xor(v, 8); }

// async 16B global->LDS; LDS dest is wave-uniform base + lane*16 (m104/m108)
#define GLOAD16(g, l) \
    __builtin_amdgcn_global_load_lds( \
        (const __attribute__((address_space(1))) void*)(g), \
        (__attribute__((address_space(3))) void*)(l), 16, 0, 0)

// counted waits + scheduling fence (rule #18: sched_barrier after asm wait)
#define VMCNT6() { asm volatile("s_waitcnt vmcnt(6)" ::: "memory"); \
                   __builtin_amdgcn_sched_barrier(0); }
#define VMCNT0() { asm volatile("s_waitcnt vmcnt(0)" ::: "memory"); \
                   __builtin_amdgcn_sched_barrier(0); }

// ---------------------------------------------------------------------------
// Prep: Wt[j][k] = bf16(We[k][j] + (k==j))   (128x384, residual folded in)
//       Wtn[j][k] = bf16(Wn[k][j])           (128x256)
// ---------------------------------------------------------------------------
__global__ void prep_w(const float* __restrict__ We, const float* __restrict__ Wn,
                       __bf16* __restrict__ Wt, __bf16* __restrict__ Wtn)
{
    const int t = blockIdx.x * 256 + threadIdx.x;
    if (t < 128 * 384) {
        const int j = t / 384, k = t % 384;
        Wt[t] = (__bf16)(We[(size_t)k * 128 + j] + ((k == j) ? 1.0f : 0.0f));
    } else if (t < 128 * 384 + 128 * 256) {
        const int u = t - 128 * 384;
        const int j = u / 256, k = u % 256;
        Wtn[u] = (__bf16)Wn[(size_t)k * 128 + j];
    }
}

// ---------------------------------------------------------------------------
// Edge update via MFMA, async-staged + counted-vmcnt pipeline (T3/T4-lite):
//  - 2-buffer LDS; stage(kt+2) issued after post-MFMA barrier; vmcnt(6) at
//    loop top (never 0 except last step) -> loads span 2 MFMA phases.
//  - raw s_barrier (no implicit vmcnt(0) drain), sched_barrier fences.
//  - degree counting fused here (atomics drained by initial __syncthreads).
// ---------------------------------------------------------------------------
#define ESTAGE(b, kt) { \
    _Pragma("unroll") \
    for (int r = 0; r < 4; ++r) { \
        const float* g = ((kt) < 4) ? baseE[r] + (kt) * 32 \
                       : ((kt) < 8) ? baseS[r] + ((kt) - 4) * 32 \
                                    : baseT[r] + ((kt) - 8) * 32; \
        GLOAD16(g, &Asf[b][(wid * 4 + r) * 256]); \
    } \
    _Pragma("unroll") \
    for (int r = 0; r < 2; ++r) \
        GLOAD16(baseW[r] + (kt) * 32, &Btf[b][(wid * 2 + r) * 512]); }

#define EFRAG_MFMA(b) { \
    bf16x8 afm[2]; \
    _Pragma("unroll") \
    for (int mt = 0; mt < 2; ++mt) { \
        const int row = wid * 32 + mt * 16 + li; \
        const int swz = li & 7; \
        const f32x4 va = *(const f32x4*)&Asf[b][row * 32 + (((lg * 2) ^ swz) << 2)]; \
        const f32x4 vb = *(const f32x4*)&Asf[b][row * 32 + (((lg * 2 + 1) ^ swz) << 2)]; \
        bf16x8 af; \
        af[0] = (__bf16)va[0]; af[1] = (__bf16)va[1]; \
        af[2] = (__bf16)va[2]; af[3] = (__bf16)va[3]; \
        af[4] = (__bf16)vb[0]; af[5] = (__bf16)vb[1]; \
        af[6] = (__bf16)vb[2]; af[7] = (__bf16)vb[3]; \
        afm[mt] = af; \
    } \
    _Pragma("unroll") \
    for (int nt = 0; nt < 8; ++nt) { \
        const int col = nt * 16 + li; \
        const bf16x8 bfr = \
            *(const bf16x8*)&Btf[b][col * 32 + ((lg ^ ((li >> 1) & 3)) << 3)]; \
        acc[0][nt] = __builtin_amdgcn_mfma_f32_16x16x32_bf16(afm[0], bfr, acc[0][nt], 0, 0, 0); \
        acc[1][nt] = __builtin_amdgcn_mfma_f32_16x16x32_bf16(afm[1], bfr, acc[1][nt], 0, 0, 0); \
    } }

__launch_bounds__(256)
__global__ void edge_kernel(const float* __restrict__ nodef,
                            const float* __restrict__ edgef,
                            const int*   __restrict__ eidx,
                            const __bf16* __restrict__ Wt,
                            const float* __restrict__ be,
                            const float* __restrict__ gamma_e,
                            const float* __restrict__ beta_e,
                            float* __restrict__ new_edges,
                            __bf16* __restrict__ sh,
                            int* __restrict__ cnt)
{
    __shared__ float  Asf[2][4096];   // [buf][row*32 + chunk-swizzled k] f32
    __shared__ __bf16 Btf[2][4096];   // [buf][col*32 + chunk-swizzled k] bf16
    __shared__ int s_src[128], s_tgt[128];

    const int tid = threadIdx.x;
    const int e0  = blockIdx.x * 128;

    if (tid < 128) {
        const int v = eidx[min(e0 + tid, N_EDGES - 1)];
        s_src[tid] = v;
        if (e0 + tid < N_EDGES) atomicAdd(&cnt[v], 1);       // fused count
    } else {
        const int v = eidx[N_EDGES + min(e0 + tid - 128, N_EDGES - 1)];
        s_tgt[tid - 128] = v;
        if (e0 + tid - 128 < N_EDGES) atomicAdd(&cnt[v], 1); // fused count
    }
    __syncthreads();   // drains the atomics + s_src/s_tgt writes (vmcnt(0))

    const int wid  = tid >> 6;
    const int lane = tid & 63;
    const int li   = lane & 15;
    const int lg   = lane >> 4;

    // per-thread pre-swizzled global base pointers (kt-independent)
    const float* baseE[4];
    const float* baseS[4];
    const float* baseT[4];
    #pragma unroll
    for (int r = 0; r < 4; ++r) {
        const int idx = (wid * 4 + r) * 64 + lane;    // flat 16B-chunk id
        const int row = idx >> 3;
        const int ch  = idx & 7;
        const int cg  = ch ^ (row & 7);
        const int er  = min(e0 + row, N_EDGES - 1);
        baseE[r] = edgef + (size_t)er * D + cg * 4;
        baseS[r] = nodef + (size_t)s_src[row] * D + cg * 4;
        baseT[r] = nodef + (size_t)s_tgt[row] * D + cg * 4;
    }
    const __bf16* baseW[2];
    #pragma unroll
    for (int r = 0; r < 2; ++r) {
        const int idx = (wid * 2 + r) * 64 + lane;
        const int col = idx >> 2;
        const int ch  = idx & 3;
        const int cg  = ch ^ ((col >> 1) & 3);
        baseW[r] = Wt + (size_t)col * 384 + cg * 8;
    }

    f32x4 acc[2][8];
    const f32x4 zero = {0.f, 0.f, 0.f, 0.f};
    #pragma unroll
    for (int m = 0; m < 2; ++m)
        #pragma unroll
        for (int n = 0; n < 8; ++n) acc[m][n] = zero;

    ESTAGE(0, 0);
    ESTAGE(1, 1);
    #pragma unroll
    for (int kt = 0; kt < 12; ++kt) {
        const int b = kt & 1;
        if (kt < 11) { VMCNT6(); } else { VMCNT0(); }   // own stage(kt) done
        __builtin_amdgcn_s_barrier();                    // tile ready block-wide
        EFRAG_MFMA(b);
        if (kt < 11) {
            __builtin_amdgcn_s_barrier();                // all waves done reading
            if (kt < 10) ESTAGE(b, kt + 2);              // flies across 2 phases
        }
    }

    // ---- epilogue: bias + LN + store (+ bf16 shadow); residual is in Wt ----
    float g[8], bt_[8], bias[8];
    #pragma unroll
    for (int nt = 0; nt < 8; ++nt) {
        const int col = nt * 16 + li;
        g[nt]    = gamma_e[col];
        bt_[nt]  = beta_e[col];
        bias[nt] = be[col];
    }

    #pragma unroll
    for (int mt = 0; mt < 2; ++mt) {
        #pragma unroll
        for (int r = 0; r < 4; ++r) {
            const int rl = wid * 32 + mt * 16 + lg * 4 + r;
            const int e  = e0 + rl;
            float x[8];
            float s = 0.f;
            #pragma unroll
            for (int nt = 0; nt < 8; ++nt) {
                x[nt] = acc[mt][nt][r] + bias[nt];
                s += x[nt];
            }
            ROWRED(s);
            const float mean = s * 0.0078125f;
            float vs = 0.f;
            #pragma unroll
            for (int nt = 0; nt < 8; ++nt) { const float d_ = x[nt] - mean; vs = fmaf(d_, d_, vs); }
            ROWRED(vs);
            const float rstd = rsqrtf(vs * 0.0078125f + LN_EPS);
            if (e < N_EDGES) {
                const size_t ec = (size_t)e;
                float y[8];
                #pragma unroll
                for (int nt = 0; nt < 8; ++nt)
                    y[nt] = fmaf((x[nt] - mean) * rstd, g[nt], bt_[nt]);
                #pragma unroll
                for (int nt = 0; nt < 8; ++nt)
                    new_edges[ec * D + nt * 16 + li] = y[nt];
                if (sh) {
                    #pragma unroll
                    for (int nt = 0; nt < 8; ++nt)
                        sh[ec * D + nt * 16 + li] = (__bf16)y[nt];
                }
            }
        }
    }
}

// ---------------------------------------------------------------------------
// Node update via MFMA (unchanged; not the bottleneck).
// ---------------------------------------------------------------------------
#define NSTORE() { \
    bf16x8 a0, a1; \
    a0[0] = (__bf16)v0.x; a0[1] = (__bf16)v0.y; a0[2] = (__bf16)v0.z; a0[3] = (__bf16)v0.w; \
    a0[4] = (__bf16)v1.x; a0[5] = (__bf16)v1.y; a0[6] = (__bf16)v1.z; a0[7] = (__bf16)v1.w; \
    a1[0] = (__bf16)v2.x; a1[1] = (__bf16)v2.y; a1[2] = (__bf16)v2.z; a1[3] = (__bf16)v2.w; \
    a1[4] = (__bf16)v3.x; a1[5] = (__bf16)v3.y; a1[6] = (__bf16)v3.z; a1[7] = (__bf16)v3.w; \
    *(bf16x8*)&NAs[lrow][lhalf * 16]     = a0; \
    *(bf16x8*)&NAs[lrow][lhalf * 16 + 8] = a1; \
    *(bf16x8*)&NBt[lrow][lhalf * 16]     = wb0; \
    *(bf16x8*)&NBt[lrow][lhalf * 16 + 8] = wb1; }

#define NLOAD(kt) { \
    const float* ab = ((kt) < 4) ? nodp + (kt) * 32 : aggp + ((kt) - 4) * 32; \
    v0 = ((const float4*)ab)[0]; v1 = ((const float4*)ab)[1]; \
    v2 = ((const float4*)ab)[2]; v3 = ((const float4*)ab)[3]; \
    wb0 = *(const bf16x8*)(wbp + (kt) * 32); \
    wb1 = *(const bf16x8*)(wbp + (kt) * 32 + 8); }

__launch_bounds__(256)
__global__ void node_kernel(const float* __restrict__ nodef,
                            const __bf16* __restrict__ Wtn,
                            const float* __restrict__ bn,
                            const float* __restrict__ gamma_n,
                            const float* __restrict__ beta_n,
                            const float* __restrict__ edge_mean,
                            float* __restrict__ new_nodes)
{
    __shared__ __bf16 NAs[128][40];
    __shared__ __bf16 NBt[128][40];

    const int tid = threadIdx.x;
    const int n0  = blockIdx.x * 128;

    const int lrow  = tid >> 1;
    const int lhalf = tid & 1;
    const size_t nclamp = (size_t)min(n0 + lrow, N_NODES - 1);

    const float* nodp = nodef     + nclamp * D + lhalf * 16;
    const float* aggp = edge_mean + nclamp * D + lhalf * 16;
    const __bf16* wbp = Wtn + (size_t)lrow * 256 + lhalf * 16;

    const int wid  = tid >> 6;
    const int lane = tid & 63;
    const int li   = lane & 15;
    const int lg   = lane >> 4;
    const int k0   = lg * 8;

    f32x4 acc[2][8];
    const f32x4 zero = {0.f, 0.f, 0.f, 0.f};
    #pragma unroll
    for (int m = 0; m < 2; ++m)
        #pragma unroll
        for (int n = 0; n < 8; ++n) acc[m][n] = zero;

    float4 v0, v1, v2, v3;
    bf16x8 wb0, wb1;

    #pragma unroll
    for (int kt = 0; kt < 8; ++kt) {
        NLOAD(kt);
        __syncthreads();
        NSTORE();
        __syncthreads();
        const bf16x8 af0 = *(const bf16x8*)&NAs[wid * 32 + li][k0];
        const bf16x8 af1 = *(const bf16x8*)&NAs[wid * 32 + 16 + li][k0];
        #pragma unroll
        for (int nt = 0; nt < 8; ++nt) {
            const bf16x8 bfr = *(const bf16x8*)&NBt[nt * 16 + li][k0];
            acc[0][nt] = __builtin_amdgcn_mfma_f32_16x16x32_bf16(af0, bfr, acc[0][nt], 0, 0, 0);
            acc[1][nt] = __builtin_amdgcn_mfma_f32_16x16x32_bf16(af1, bfr, acc[1][nt], 0, 0, 0);
        }
    }

    float g[8], bt_[8], bias[8];
    #pragma unroll
    for (int nt = 0; nt < 8; ++nt) {
        const int col = nt * 16 + li;
        g[nt]    = gamma_n[col];
        bt_[nt]  = beta_n[col];
        bias[nt] = bn[col];
    }

    #pragma unroll
    for (int mt = 0; mt < 2; ++mt) {
        #pragma unroll
        for (int r = 0; r < 4; ++r) {
            const int rl = wid * 32 + mt * 16 + lg * 4 + r;
            const int n  = n0 + rl;
            const size_t nc = (size_t)min(n, N_NODES - 1);
            float x[8];
            float s = 0.f;
            #pragma unroll
            for (int nt = 0; nt < 8; ++nt) {
                x[nt] = acc[mt][nt][r] + bias[nt] + nodef[nc * D + nt * 16 + li];
                s += x[nt];
            }
            ROWRED(s);
            const float mean = s * 0.0078125f;
            float vs = 0.f;
            #pragma unroll
            for (int nt = 0; nt < 8; ++nt) { const float d_ = x[nt] - mean; vs = fmaf(d_, d_, vs); }
            ROWRED(vs);
            const float rstd = rsqrtf(vs * 0.0078125f + LN_EPS);
            if (n < N_NODES) {
                #pragma unroll
                for (int nt = 0; nt < 8; ++nt)
                    new_nodes[nc * D + nt * 16 + li] =
                        fmaf((x[nt] - mean) * rstd, g[nt], bt_[nt]);
            }
        }
    }
}

// ---------------------------------------------------------------------------
// CSR build: (count fused in edge_kernel) -> hierarchical scan -> fill
// ---------------------------------------------------------------------------
__global__ void scan1(const int* __restrict__ cnt, int* __restrict__ excl,
                      int* __restrict__ bsum)
{
    const int tid = threadIdx.x, lane = tid & 63, wid = tid >> 6;
    const int i = blockIdx.x * 256 + tid;
    const int v = (i < N_NODES) ? cnt[i] : 0;
    int x = v;
    #pragma unroll
    for (int s = 1; s < 64; s <<= 1) { const int t = __shfl_up(x, s); if (lane >= s) x += t; }
    __shared__ int ws[4], wb[4];
    if (lane == 63) ws[wid] = x;
    __syncthreads();
    if (tid == 0) {
        int run = 0;
        #pragma unroll
        for (int w = 0; w < 4; ++w) { wb[w] = run; run += ws[w]; }
        bsum[blockIdx.x] = run;
    }
    __syncthreads();
    if (i < N_NODES) excl[i] = wb[wid] + x - v;
}

__global__ void scan2(int* __restrict__ bsum, int* __restrict__ offs)
{
    __shared__ int ws[4], wb[4];
    __shared__ int sbase;
    const int tid = threadIdx.x, lane = tid & 63, wid = tid >> 6;
    if (tid == 0) sbase = 0;
    __syncthreads();
    for (int chunk = 0; chunk < NB; chunk += 256) {
        const int i = chunk + tid;
        const int v = (i < NB) ? bsum[i] : 0;
        int x = v;
        #pragma unroll
        for (int s = 1; s < 64; s <<= 1) { const int t = __shfl_up(x, s); if (lane >= s) x += t; }
        if (lane == 63) ws[wid] = x;
        __syncthreads();
        if (tid == 0) {
            int run = sbase;
            #pragma unroll
            for (int w = 0; w < 4; ++w) { wb[w] = run; run += ws[w]; }
            sbase = run;
        }
        __syncthreads();
        if (i < NB) bsum[i] = wb[wid] + x - v;
        __syncthreads();
    }
    if (tid == 0) offs[N_NODES] = sbase;
}

__global__ void scan3(const int* __restrict__ excl, const int* __restrict__ bsum,
                      int* __restrict__ offs, int* __restrict__ cursor)
{
    const int i = blockIdx.x * 256 + threadIdx.x;
    if (i < N_NODES) {
        const int o = excl[i] + bsum[i >> 8];
        offs[i] = o;
        cursor[i] = o;
    }
}

__global__ void fill_kernel(const int* __restrict__ eidx,
                            int* __restrict__ cursor,
                            int* __restrict__ list)
{
    const int i = blockIdx.x * blockDim.x + threadIdx.x;
    if (i < 2 * N_EDGES) {
        const int n   = eidx[i];
        const int pos = atomicAdd(&cursor[n], 1);
        list[pos] = (i < N_EDGES) ? i : i - N_EDGES;
    }
}

// ---------------------------------------------------------------------------
// Aggregation: one wave per node, unroll-8 (MLP=8). SH=true reads bf16 shadow.
// ---------------------------------------------------------------------------
template<bool SH>
__launch_bounds__(256)
__global__ void aggregate_kernel(const float* __restrict__ nef,
                                 const __bf16* __restrict__ sh,
                                 const int* __restrict__ offs,
                                 const int* __restrict__ list,
                                 float* __restrict__ edge_mean)
{
    const int lane   = threadIdx.x & 63;
    const int gwave  = (blockIdx.x * 256 + threadIdx.x) >> 6;
    const int nwaves = gridDim.x * 4;

    for (int n = gwave; n < N_NODES; n += nwaves) {
        const int beg = offs[n], end = offs[n + 1];
        float ax0 = 0.f, ay0 = 0.f, ax1 = 0.f, ay1 = 0.f;
        float ax2 = 0.f, ay2 = 0.f, ax3 = 0.f, ay3 = 0.f;
        int j = beg;
        if (SH) {
            const unsigned int* base = (const unsigned int*)sh;
            for (; j + 8 <= end; j += 8) {
                unsigned int u[8];
                #pragma unroll
                for (int q = 0; q < 8; ++q)
                    u[q] = base[(size_t)list[j + q] * 64 + lane];
                ax0 += __uint_as_float(u[0] << 16) + __uint_as_float(u[4] << 16);
                ay0 += __uint_as_float(u[0] & 0xffff0000u) + __uint_as_float(u[4] & 0xffff0000u);
                ax1 += __uint_as_float(u[1] << 16) + __uint_as_float(u[5] << 16);
                ay1 += __uint_as_float(u[1] & 0xffff0000u) + __uint_as_float(u[5] & 0xffff0000u);
                ax2 += __uint_as_float(u[2] << 16) + __uint_as_float(u[6] << 16);
                ay2 += __uint_as_float(u[2] & 0xffff0000u) + __uint_as_float(u[6] & 0xffff0000u);
                ax3 += __uint_as_float(u[3] << 16) + __uint_as_float(u[7] << 16);
                ay3 += __uint_as_float(u[3] & 0xffff0000u) + __uint_as_float(u[7] & 0xffff0000u);
            }
            for (; j < end; ++j) {
                const unsigned int u = base[(size_t)list[j] * 64 + lane];
                ax0 += __uint_as_float(u << 16); ay0 += __uint_as_float(u & 0xffff0000u);
            }
        } else {
            for (; j + 4 <= end; j += 4) {
                const int e0 = list[j], e1 = list[j + 1], e2 = list[j + 2], e3 = list[j + 3];
                const float2 w0 = ((const float2*)(nef + (size_t)e0 * D))[lane];
                const float2 w1 = ((const float2*)(nef + (size_t)e1 * D))[lane];
                const float2 w2 = ((const float2*)(nef + (size_t)e2 * D))[lane];
                const float2 w3 = ((const float2*)(nef + (size_t)e3 * D))[lane];
                ax0 += w0.x; ay0 += w0.y; ax1 += w1.x; ay1 += w1.y;
                ax2 += w2.x; ay2 += w2.y; ax3 += w3.x; ay3 += w3.y;
            }
            for (; j < end; ++j) {
                const float2 w = ((const float2*)(nef + (size_t)list[j] * D))[lane];
                ax0 += w.x; ay0 += w.y;
            }
        }
        const float sx = (ax0 + ax1) + (ax2 + ax3);
        const float sy = (ay0 + ay1) + (ay2 + ay3);
        const float inv = 1.0f / ((float)(end - beg) + CNT_EPS);
        ((float2*)(edge_mean + (size_t)n * D))[lane] = make_float2(sx * inv, sy * inv);
    }
}

extern "C" void kernel_launch(void* const* d_in, const int* in_sizes, int n_in,
                              void* d_out, int out_size, void* d_ws, size_t ws_size,
                              hipStream_t stream) {
    const float* nodef   = (const float*)d_in[0];
    const float* edgef   = (const float*)d_in[1];
    const int*   eidx    = (const int*)d_in[2];
    const float* We      = (const float*)d_in[3];
    const float* be      = (const float*)d_in[4];
    const float* gamma_e = (const float*)d_in[5];
    const float* beta_e  = (const float*)d_in[6];
    const float* Wn      = (const float*)d_in[7];
    const float* bn      = (const float*)d_in[8];
    const float* gamma_n = (const float*)d_in[9];
    const float* beta_n  = (const float*)d_in[10];

    float* new_nodes = (float*)d_out;                      // also edge_mean buffer
    float* new_edges = (float*)d_out + (size_t)N_NODES * D;

    // workspace layout
    char* p = (char*)d_ws;
    __bf16* Wt  = (__bf16*)p;  p += 128 * 384 * 2;     // 98304
    __bf16* Wtn = (__bf16*)p;  p += 128 * 256 * 2;     // 65536
    int* cnt    = (int*)p;     p += (size_t)N_NODES * 4;
    int* excl   = (int*)p;     p += (size_t)N_NODES * 4;
    int* offs   = (int*)p;     p += (size_t)(N_NODES + 2) * 4;
    int* cursor = (int*)p;     p += (size_t)N_NODES * 4;
    int* bsum   = (int*)p;     p += 2048;
    int* list   = (int*)p;     p += (size_t)2 * N_EDGES * 4;
    const size_t base_bytes = (size_t)(p - (char*)d_ws);
    const size_t shadow_bytes = (size_t)N_EDGES * D * 2;
    __bf16* shadow = nullptr;
    if (ws_size >= base_bytes + shadow_bytes) shadow = (__bf16*)p;

    hipMemsetAsync(cnt, 0, (size_t)N_NODES * sizeof(int), stream);

    prep_w<<<320, 256, 0, stream>>>(We, Wn, Wt, Wtn);

    edge_kernel<<<(N_EDGES + 127) / 128, 256, 0, stream>>>(
        nodef, edgef, eidx, Wt, be, gamma_e, beta_e, new_edges, shadow, cnt);

    scan1<<<NB, 256, 0, stream>>>(cnt, excl, bsum);
    scan2<<<1, 256, 0, stream>>>(bsum, offs);
    scan3<<<NB, 256, 0, stream>>>(excl, bsum, offs, cursor);
    fill_kernel<<<(2 * N_EDGES + 255) / 256, 256, 0, stream>>>(eidx, cursor, list);

    if (shadow)
        aggregate_kernel<true><<<2048, 256, 0, stream>>>(new_edges, shadow, offs, list, new_nodes);
    else
        aggregate_kernel<false><<<2048, 256, 0, stream>>>(new_edges, nullptr, offs, list, new_nodes);

    node_kernel<<<(N_NODES + 127) / 128, 256, 0, stream>>>(
        nodef, Wtn, bn, gamma_n, beta_n, new_nodes, new_nodes);
}

// Round 14
// 786.482 us; speedup vs baseline: 1.3283x; 1.0414x over previous
//
#include <hip/hip_runtime.h>

#define N_NODES 100000
#define N_EDGES 1000000
#define D 128
#define NB ((N_NODES + 255) / 256)   // 391 scan blocks
#define LN_EPS 1e-5f
#define CNT_EPS 1e-10f

typedef __bf16 bf16x8 __attribute__((ext_vector_type(8)));
typedef __bf16 bf16x4 __attribute__((ext_vector_type(4)));
typedef float  f32x4  __attribute__((ext_vector_type(4)));

#define ROWRED(v) { v += __shfl_xor(v, 1); v += __shfl_xor(v, 2); \
                    v += __shfl_xor(v, 4); v += __shfl_xor(v, 8); }

// async 16B global->LDS; LDS dest is wave-uniform base + lane*16 (m104/m108)
#define GLOAD16(g, l) \
    __builtin_amdgcn_global_load_lds( \
        (const __attribute__((address_space(1))) void*)(g), \
        (__attribute__((address_space(3))) void*)(l), 16, 0, 0)

// ---------------------------------------------------------------------------
// Prep: Wt[j][k] = bf16(We[k][j] + (k==j))   (128x384, residual folded in)
//       Wtn[j][k] = bf16(Wn[k][j])           (128x256)
// ---------------------------------------------------------------------------
__global__ void prep_w(const float* __restrict__ We, const float* __restrict__ Wn,
                       __bf16* __restrict__ Wt, __bf16* __restrict__ Wtn)
{
    const int t = blockIdx.x * 256 + threadIdx.x;
    if (t < 128 * 384) {
        const int j = t / 384, k = t % 384;
        Wt[t] = (__bf16)(We[(size_t)k * 128 + j] + ((k == j) ? 1.0f : 0.0f));
    } else if (t < 128 * 384 + 128 * 256) {
        const int u = t - 128 * 384;
        const int j = u / 256, k = u % 256;
        Wtn[u] = (__bf16)Wn[(size_t)k * 128 + j];
    }
}

// ---------------------------------------------------------------------------
// Edge update via MFMA, async-staged (R11 schedule — measured 3.77 TB/s):
//  - double-buffered LDS, ONE __syncthreads per K-step (implicit vmcnt drain)
//  - all staging via global_load_lds w=16, XOR-pre-swizzled global source
//  - degree counting fused (atomics drained by the initial __syncthreads)
//  - residual folded into Wt; epilogue = bias + LN + f32 & bf16-shadow store
// ---------------------------------------------------------------------------
#define ESTAGE(b, kt) { \
    _Pragma("unroll") \
    for (int r = 0; r < 4; ++r) { \
        const float* g = ((kt) < 4) ? baseE[r] + (kt) * 32 \
                       : ((kt) < 8) ? baseS[r] + ((kt) - 4) * 32 \
                                    : baseT[r] + ((kt) - 8) * 32; \
        GLOAD16(g, &Asf[b][(wid * 4 + r) * 256]); \
    } \
    _Pragma("unroll") \
    for (int r = 0; r < 2; ++r) \
        GLOAD16(baseW[r] + (kt) * 32, &Btf[b][(wid * 2 + r) * 512]); }

#define EFRAG_MFMA(b) { \
    bf16x8 afm[2]; \
    _Pragma("unroll") \
    for (int mt = 0; mt < 2; ++mt) { \
        const int row = wid * 32 + mt * 16 + li; \
        const int swz = li & 7; \
        const f32x4 va = *(const f32x4*)&Asf[b][row * 32 + (((lg * 2) ^ swz) << 2)]; \
        const f32x4 vb = *(const f32x4*)&Asf[b][row * 32 + (((lg * 2 + 1) ^ swz) << 2)]; \
        bf16x8 af; \
        af[0] = (__bf16)va[0]; af[1] = (__bf16)va[1]; \
        af[2] = (__bf16)va[2]; af[3] = (__bf16)va[3]; \
        af[4] = (__bf16)vb[0]; af[5] = (__bf16)vb[1]; \
        af[6] = (__bf16)vb[2]; af[7] = (__bf16)vb[3]; \
        afm[mt] = af; \
    } \
    _Pragma("unroll") \
    for (int nt = 0; nt < 8; ++nt) { \
        const int col = nt * 16 + li; \
        const bf16x8 bfr = \
            *(const bf16x8*)&Btf[b][col * 32 + ((lg ^ ((li >> 1) & 3)) << 3)]; \
        acc[0][nt] = __builtin_amdgcn_mfma_f32_16x16x32_bf16(afm[0], bfr, acc[0][nt], 0, 0, 0); \
        acc[1][nt] = __builtin_amdgcn_mfma_f32_16x16x32_bf16(afm[1], bfr, acc[1][nt], 0, 0, 0); \
    } }

__launch_bounds__(256)
__global__ void edge_kernel(const float* __restrict__ nodef,
                            const float* __restrict__ edgef,
                            const int*   __restrict__ eidx,
                            const __bf16* __restrict__ Wt,
                            const float* __restrict__ be,
                            const float* __restrict__ gamma_e,
                            const float* __restrict__ beta_e,
                            float* __restrict__ new_edges,
                            __bf16* __restrict__ sh,
                            int* __restrict__ cnt)
{
    __shared__ float  Asf[2][4096];   // [buf][row*32 + chunk-swizzled k] f32
    __shared__ __bf16 Btf[2][4096];   // [buf][col*32 + chunk-swizzled k] bf16
    __shared__ int s_src[128], s_tgt[128];

    const int tid = threadIdx.x;
    const int e0  = blockIdx.x * 128;

    if (tid < 128) {
        const int v = eidx[min(e0 + tid, N_EDGES - 1)];
        s_src[tid] = v;
        if (e0 + tid < N_EDGES) atomicAdd(&cnt[v], 1);       // fused count
    } else {
        const int v = eidx[N_EDGES + min(e0 + tid - 128, N_EDGES - 1)];
        s_tgt[tid - 128] = v;
        if (e0 + tid - 128 < N_EDGES) atomicAdd(&cnt[v], 1); // fused count
    }
    __syncthreads();   // drains the atomics + s_src/s_tgt writes

    const int wid  = tid >> 6;
    const int lane = tid & 63;
    const int li   = lane & 15;
    const int lg   = lane >> 4;

    // per-thread pre-swizzled global base pointers (kt-independent)
    const float* baseE[4];
    const float* baseS[4];
    const float* baseT[4];
    #pragma unroll
    for (int r = 0; r < 4; ++r) {
        const int idx = (wid * 4 + r) * 64 + lane;    // flat 16B-chunk id
        const int row = idx >> 3;
        const int ch  = idx & 7;
        const int cg  = ch ^ (row & 7);
        const int er  = min(e0 + row, N_EDGES - 1);
        baseE[r] = edgef + (size_t)er * D + cg * 4;
        baseS[r] = nodef + (size_t)s_src[row] * D + cg * 4;
        baseT[r] = nodef + (size_t)s_tgt[row] * D + cg * 4;
    }
    const __bf16* baseW[2];
    #pragma unroll
    for (int r = 0; r < 2; ++r) {
        const int idx = (wid * 2 + r) * 64 + lane;
        const int col = idx >> 2;
        const int ch  = idx & 3;
        const int cg  = ch ^ ((col >> 1) & 3);
        baseW[r] = Wt + (size_t)col * 384 + cg * 8;
    }

    f32x4 acc[2][8];
    const f32x4 zero = {0.f, 0.f, 0.f, 0.f};
    #pragma unroll
    for (int m = 0; m < 2; ++m)
        #pragma unroll
        for (int n = 0; n < 8; ++n) acc[m][n] = zero;

    ESTAGE(0, 0);
    __syncthreads();                      // drain prologue loads
    #pragma unroll
    for (int kt = 0; kt < 12; ++kt) {
        const int b = kt & 1;
        if (kt < 11) ESTAGE(b ^ 1, kt + 1);   // async, in flight over MFMAs
        EFRAG_MFMA(b);
        if (kt < 11) __syncthreads();         // drains next-tile loads too
    }

    // ---- epilogue: bias + LN + store (+ bf16 shadow); residual is in Wt ----
    float g[8], bt_[8], bias[8];
    #pragma unroll
    for (int nt = 0; nt < 8; ++nt) {
        const int col = nt * 16 + li;
        g[nt]    = gamma_e[col];
        bt_[nt]  = beta_e[col];
        bias[nt] = be[col];
    }

    #pragma unroll
    for (int mt = 0; mt < 2; ++mt) {
        #pragma unroll
        for (int r = 0; r < 4; ++r) {
            const int rl = wid * 32 + mt * 16 + lg * 4 + r;
            const int e  = e0 + rl;
            float x[8];
            float s = 0.f;
            #pragma unroll
            for (int nt = 0; nt < 8; ++nt) {
                x[nt] = acc[mt][nt][r] + bias[nt];
                s += x[nt];
            }
            ROWRED(s);
            const float mean = s * 0.0078125f;
            float vs = 0.f;
            #pragma unroll
            for (int nt = 0; nt < 8; ++nt) { const float d_ = x[nt] - mean; vs = fmaf(d_, d_, vs); }
            ROWRED(vs);
            const float rstd = rsqrtf(vs * 0.0078125f + LN_EPS);
            if (e < N_EDGES) {
                const size_t ec = (size_t)e;
                float y[8];
                #pragma unroll
                for (int nt = 0; nt < 8; ++nt)
                    y[nt] = fmaf((x[nt] - mean) * rstd, g[nt], bt_[nt]);
                #pragma unroll
                for (int nt = 0; nt < 8; ++nt)
                    new_edges[ec * D + nt * 16 + li] = y[nt];
                if (sh) {
                    #pragma unroll
                    for (int nt = 0; nt < 8; ++nt)
                        sh[ec * D + nt * 16 + li] = (__bf16)y[nt];
                }
            }
        }
    }
}

// ---------------------------------------------------------------------------
// Node update via MFMA (unchanged; not the bottleneck).
// ---------------------------------------------------------------------------
#define NSTORE() { \
    bf16x8 a0, a1; \
    a0[0] = (__bf16)v0.x; a0[1] = (__bf16)v0.y; a0[2] = (__bf16)v0.z; a0[3] = (__bf16)v0.w; \
    a0[4] = (__bf16)v1.x; a0[5] = (__bf16)v1.y; a0[6] = (__bf16)v1.z; a0[7] = (__bf16)v1.w; \
    a1[0] = (__bf16)v2.x; a1[1] = (__bf16)v2.y; a1[2] = (__bf16)v2.z; a1[3] = (__bf16)v2.w; \
    a1[4] = (__bf16)v3.x; a1[5] = (__bf16)v3.y; a1[6] = (__bf16)v3.z; a1[7] = (__bf16)v3.w; \
    *(bf16x8*)&NAs[lrow][lhalf * 16]     = a0; \
    *(bf16x8*)&NAs[lrow][lhalf * 16 + 8] = a1; \
    *(bf16x8*)&NBt[lrow][lhalf * 16]     = wb0; \
    *(bf16x8*)&NBt[lrow][lhalf * 16 + 8] = wb1; }

#define NLOAD(kt) { \
    const float* ab = ((kt) < 4) ? nodp + (kt) * 32 : aggp + ((kt) - 4) * 32; \
    v0 = ((const float4*)ab)[0]; v1 = ((const float4*)ab)[1]; \
    v2 = ((const float4*)ab)[2]; v3 = ((const float4*)ab)[3]; \
    wb0 = *(const bf16x8*)(wbp + (kt) * 32); \
    wb1 = *(const bf16x8*)(wbp + (kt) * 32 + 8); }

__launch_bounds__(256)
__global__ void node_kernel(const float* __restrict__ nodef,
                            const __bf16* __restrict__ Wtn,
                            const float* __restrict__ bn,
                            const float* __restrict__ gamma_n,
                            const float* __restrict__ beta_n,
                            const float* __restrict__ edge_mean,
                            float* __restrict__ new_nodes)
{
    __shared__ __bf16 NAs[128][40];
    __shared__ __bf16 NBt[128][40];

    const int tid = threadIdx.x;
    const int n0  = blockIdx.x * 128;

    const int lrow  = tid >> 1;
    const int lhalf = tid & 1;
    const size_t nclamp = (size_t)min(n0 + lrow, N_NODES - 1);

    const float* nodp = nodef     + nclamp * D + lhalf * 16;
    const float* aggp = edge_mean + nclamp * D + lhalf * 16;
    const __bf16* wbp = Wtn + (size_t)lrow * 256 + lhalf * 16;

    const int wid  = tid >> 6;
    const int lane = tid & 63;
    const int li   = lane & 15;
    const int lg   = lane >> 4;
    const int k0   = lg * 8;

    f32x4 acc[2][8];
    const f32x4 zero = {0.f, 0.f, 0.f, 0.f};
    #pragma unroll
    for (int m = 0; m < 2; ++m)
        #pragma unroll
        for (int n = 0; n < 8; ++n) acc[m][n] = zero;

    float4 v0, v1, v2, v3;
    bf16x8 wb0, wb1;

    #pragma unroll
    for (int kt = 0; kt < 8; ++kt) {
        NLOAD(kt);
        __syncthreads();
        NSTORE();
        __syncthreads();
        const bf16x8 af0 = *(const bf16x8*)&NAs[wid * 32 + li][k0];
        const bf16x8 af1 = *(const bf16x8*)&NAs[wid * 32 + 16 + li][k0];
        #pragma unroll
        for (int nt = 0; nt < 8; ++nt) {
            const bf16x8 bfr = *(const bf16x8*)&NBt[nt * 16 + li][k0];
            acc[0][nt] = __builtin_amdgcn_mfma_f32_16x16x32_bf16(af0, bfr, acc[0][nt], 0, 0, 0);
            acc[1][nt] = __builtin_amdgcn_mfma_f32_16x16x32_bf16(af1, bfr, acc[1][nt], 0, 0, 0);
        }
    }

    float g[8], bt_[8], bias[8];
    #pragma unroll
    for (int nt = 0; nt < 8; ++nt) {
        const int col = nt * 16 + li;
        g[nt]    = gamma_n[col];
        bt_[nt]  = beta_n[col];
        bias[nt] = bn[col];
    }

    #pragma unroll
    for (int mt = 0; mt < 2; ++mt) {
        #pragma unroll
        for (int r = 0; r < 4; ++r) {
            const int rl = wid * 32 + mt * 16 + lg * 4 + r;
            const int n  = n0 + rl;
            const size_t nc = (size_t)min(n, N_NODES - 1);
            float x[8];
            float s = 0.f;
            #pragma unroll
            for (int nt = 0; nt < 8; ++nt) {
                x[nt] = acc[mt][nt][r] + bias[nt] + nodef[nc * D + nt * 16 + li];
                s += x[nt];
            }
            ROWRED(s);
            const float mean = s * 0.0078125f;
            float vs = 0.f;
            #pragma unroll
            for (int nt = 0; nt < 8; ++nt) { const float d_ = x[nt] - mean; vs = fmaf(d_, d_, vs); }
            ROWRED(vs);
            const float rstd = rsqrtf(vs * 0.0078125f + LN_EPS);
            if (n < N_NODES) {
                #pragma unroll
                for (int nt = 0; nt < 8; ++nt)
                    new_nodes[nc * D + nt * 16 + li] =
                        fmaf((x[nt] - mean) * rstd, g[nt], bt_[nt]);
            }
        }
    }
}

// ---------------------------------------------------------------------------
// CSR build: (count fused in edge_kernel) -> hierarchical scan -> fill
// ---------------------------------------------------------------------------
__global__ void scan1(const int* __restrict__ cnt, int* __restrict__ excl,
                      int* __restrict__ bsum)
{
    const int tid = threadIdx.x, lane = tid & 63, wid = tid >> 6;
    const int i = blockIdx.x * 256 + tid;
    const int v = (i < N_NODES) ? cnt[i] : 0;
    int x = v;
    #pragma unroll
    for (int s = 1; s < 64; s <<= 1) { const int t = __shfl_up(x, s); if (lane >= s) x += t; }
    __shared__ int ws[4], wb[4];
    if (lane == 63) ws[wid] = x;
    __syncthreads();
    if (tid == 0) {
        int run = 0;
        #pragma unroll
        for (int w = 0; w < 4; ++w) { wb[w] = run; run += ws[w]; }
        bsum[blockIdx.x] = run;
    }
    __syncthreads();
    if (i < N_NODES) excl[i] = wb[wid] + x - v;
}

__global__ void scan2(int* __restrict__ bsum, int* __restrict__ offs)
{
    __shared__ int ws[4], wb[4];
    __shared__ int sbase;
    const int tid = threadIdx.x, lane = tid & 63, wid = tid >> 6;
    if (tid == 0) sbase = 0;
    __syncthreads();
    for (int chunk = 0; chunk < NB; chunk += 256) {
        const int i = chunk + tid;
        const int v = (i < NB) ? bsum[i] : 0;
        int x = v;
        #pragma unroll
        for (int s = 1; s < 64; s <<= 1) { const int t = __shfl_up(x, s); if (lane >= s) x += t; }
        if (lane == 63) ws[wid] = x;
        __syncthreads();
        if (tid == 0) {
            int run = sbase;
            #pragma unroll
            for (int w = 0; w < 4; ++w) { wb[w] = run; run += ws[w]; }
            sbase = run;
        }
        __syncthreads();
        if (i < NB) bsum[i] = wb[wid] + x - v;
        __syncthreads();
    }
    if (tid == 0) offs[N_NODES] = sbase;
}

__global__ void scan3(const int* __restrict__ excl, const int* __restrict__ bsum,
                      int* __restrict__ offs, int* __restrict__ cursor)
{
    const int i = blockIdx.x * 256 + threadIdx.x;
    if (i < N_NODES) {
        const int o = excl[i] + bsum[i >> 8];
        offs[i] = o;
        cursor[i] = o;
    }
}

__global__ void fill_kernel(const int* __restrict__ eidx,
                            int* __restrict__ cursor,
                            int* __restrict__ list)
{
    const int i = blockIdx.x * blockDim.x + threadIdx.x;
    if (i < 2 * N_EDGES) {
        const int n   = eidx[i];
        const int pos = atomicAdd(&cursor[n], 1);
        list[pos] = (i < N_EDGES) ? i : i - N_EDGES;
    }
}

// ---------------------------------------------------------------------------
// Aggregation: one wave per node, unroll-8 (MLP=8). SH=true reads bf16 shadow.
// ---------------------------------------------------------------------------
template<bool SH>
__launch_bounds__(256)
__global__ void aggregate_kernel(const float* __restrict__ nef,
                                 const __bf16* __restrict__ sh,
                                 const int* __restrict__ offs,
                                 const int* __restrict__ list,
                                 float* __restrict__ edge_mean)
{
    const int lane   = threadIdx.x & 63;
    const int gwave  = (blockIdx.x * 256 + threadIdx.x) >> 6;
    const int nwaves = gridDim.x * 4;

    for (int n = gwave; n < N_NODES; n += nwaves) {
        const int beg = offs[n], end = offs[n + 1];
        float ax0 = 0.f, ay0 = 0.f, ax1 = 0.f, ay1 = 0.f;
        float ax2 = 0.f, ay2 = 0.f, ax3 = 0.f, ay3 = 0.f;
        int j = beg;
        if (SH) {
            const unsigned int* base = (const unsigned int*)sh;
            for (; j + 8 <= end; j += 8) {
                unsigned int u[8];
                #pragma unroll
                for (int q = 0; q < 8; ++q)
                    u[q] = base[(size_t)list[j + q] * 64 + lane];
                ax0 += __uint_as_float(u[0] << 16) + __uint_as_float(u[4] << 16);
                ay0 += __uint_as_float(u[0] & 0xffff0000u) + __uint_as_float(u[4] & 0xffff0000u);
                ax1 += __uint_as_float(u[1] << 16) + __uint_as_float(u[5] << 16);
                ay1 += __uint_as_float(u[1] & 0xffff0000u) + __uint_as_float(u[5] & 0xffff0000u);
                ax2 += __uint_as_float(u[2] << 16) + __uint_as_float(u[6] << 16);
                ay2 += __uint_as_float(u[2] & 0xffff0000u) + __uint_as_float(u[6] & 0xffff0000u);
                ax3 += __uint_as_float(u[3] << 16) + __uint_as_float(u[7] << 16);
                ay3 += __uint_as_float(u[3] & 0xffff0000u) + __uint_as_float(u[7] & 0xffff0000u);
            }
            for (; j < end; ++j) {
                const unsigned int u = base[(size_t)list[j] * 64 + lane];
                ax0 += __uint_as_float(u << 16); ay0 += __uint_as_float(u & 0xffff0000u);
            }
        } else {
            for (; j + 4 <= end; j += 4) {
                const int e0 = list[j], e1 = list[j + 1], e2 = list[j + 2], e3 = list[j + 3];
                const float2 w0 = ((const float2*)(nef + (size_t)e0 * D))[lane];
                const float2 w1 = ((const float2*)(nef + (size_t)e1 * D))[lane];
                const float2 w2 = ((const float2*)(nef + (size_t)e2 * D))[lane];
                const float2 w3 = ((const float2*)(nef + (size_t)e3 * D))[lane];
                ax0 += w0.x; ay0 += w0.y; ax1 += w1.x; ay1 += w1.y;
                ax2 += w2.x; ay2 += w2.y; ax3 += w3.x; ay3 += w3.y;
            }
            for (; j < end; ++j) {
                const float2 w = ((const float2*)(nef + (size_t)list[j] * D))[lane];
                ax0 += w.x; ay0 += w.y;
            }
        }
        const float sx = (ax0 + ax1) + (ax2 + ax3);
        const float sy = (ay0 + ay1) + (ay2 + ay3);
        const float inv = 1.0f / ((float)(end - beg) + CNT_EPS);
        ((float2*)(edge_mean + (size_t)n * D))[lane] = make_float2(sx * inv, sy * inv);
    }
}

extern "C" void kernel_launch(void* const* d_in, const int* in_sizes, int n_in,
                              void* d_out, int out_size, void* d_ws, size_t ws_size,
                              hipStream_t stream) {
    const float* nodef   = (const float*)d_in[0];
    const float* edgef   = (const float*)d_in[1];
    const int*   eidx    = (const int*)d_in[2];
    const float* We      = (const float*)d_in[3];
    const float* be      = (const float*)d_in[4];
    const float* gamma_e = (const float*)d_in[5];
    const float* beta_e  = (const float*)d_in[6];
    const float* Wn      = (const float*)d_in[7];
    const float* bn      = (const float*)d_in[8];
    const float* gamma_n = (const float*)d_in[9];
    const float* beta_n  = (const float*)d_in[10];

    float* new_nodes = (float*)d_out;                      // also edge_mean buffer
    float* new_edges = (float*)d_out + (size_t)N_NODES * D;

    // workspace layout
    char* p = (char*)d_ws;
    __bf16* Wt  = (__bf16*)p;  p += 128 * 384 * 2;     // 98304
    __bf16* Wtn = (__bf16*)p;  p += 128 * 256 * 2;     // 65536
    int* cnt    = (int*)p;     p += (size_t)N_NODES * 4;
    int* excl   = (int*)p;     p += (size_t)N_NODES * 4;
    int* offs   = (int*)p;     p += (size_t)(N_NODES + 2) * 4;
    int* cursor = (int*)p;     p += (size_t)N_NODES * 4;
    int* bsum   = (int*)p;     p += 2048;
    int* list   = (int*)p;     p += (size_t)2 * N_EDGES * 4;
    const size_t base_bytes = (size_t)(p - (char*)d_ws);
    const size_t shadow_bytes = (size_t)N_EDGES * D * 2;
    __bf16* shadow = nullptr;
    if (ws_size >= base_bytes + shadow_bytes) shadow = (__bf16*)p;

    hipMemsetAsync(cnt, 0, (size_t)N_NODES * sizeof(int), stream);

    prep_w<<<320, 256, 0, stream>>>(We, Wn, Wt, Wtn);

    edge_kernel<<<(N_EDGES + 127) / 128, 256, 0, stream>>>(
        nodef, edgef, eidx, Wt, be, gamma_e, beta_e, new_edges, shadow, cnt);

    scan1<<<NB, 256, 0, stream>>>(cnt, excl, bsum);
    scan2<<<1, 256, 0, stream>>>(bsum, offs);
    scan3<<<NB, 256, 0, stream>>>(excl, bsum, offs, cursor);
    fill_kernel<<<(2 * N_EDGES + 255) / 256, 256, 0, stream>>>(eidx, cursor, list);

    if (shadow)
        aggregate_kernel<true><<<2048, 256, 0, stream>>>(new_edges, shadow, offs, list, new_nodes);
    else
        aggregate_kernel<false><<<2048, 256, 0, stream>>>(new_edges, nullptr, offs, list, new_nodes);

    node_kernel<<<(N_NODES + 127) / 128, 256, 0, stream>>>(
        nodef, Wtn, bn, gamma_n, beta_n, new_nodes, new_nodes);
}

// Round 15
// 670.553 us; speedup vs baseline: 1.5579x; 1.1729x over previous
//
#include <hip/hip_runtime.h>

#define N_NODES 100000
#define N_EDGES 1000000
#define D 128
#define NB ((N_NODES + 255) / 256)   // 391 scan blocks
#define LN_EPS 1e-5f
#define CNT_EPS 1e-10f

typedef __bf16 bf16x8 __attribute__((ext_vector_type(8)));
typedef __bf16 bf16x4 __attribute__((ext_vector_type(4)));
typedef float  f32x4  __attribute__((ext_vector_type(4)));

#define ROWRED(v) { v += __shfl_xor(v, 1); v += __shfl_xor(v, 2); \
                    v += __shfl_xor(v, 4); v += __shfl_xor(v, 8); }

// async 16B global->LDS; LDS dest is wave-uniform base + lane*16 (m104/m108)
#define GLOAD16(g, l) \
    __builtin_amdgcn_global_load_lds( \
        (const __attribute__((address_space(1))) void*)(g), \
        (__attribute__((address_space(3))) void*)(l), 16, 0, 0)

// ---------------------------------------------------------------------------
// Prep: Wt[j][k]  = bf16(We[k][j] + (k==j))   (128x384, residual folded in)
//       Wtn[j][k] = bf16(Wn[k][j] + (k==j))   (128x256, residual folded in)
// ---------------------------------------------------------------------------
__global__ void prep_w(const float* __restrict__ We, const float* __restrict__ Wn,
                       __bf16* __restrict__ Wt, __bf16* __restrict__ Wtn)
{
    const int t = blockIdx.x * 256 + threadIdx.x;
    if (t < 128 * 384) {
        const int j = t / 384, k = t % 384;
        Wt[t] = (__bf16)(We[(size_t)k * 128 + j] + ((k == j) ? 1.0f : 0.0f));
    } else if (t < 128 * 384 + 128 * 256) {
        const int u = t - 128 * 384;
        const int j = u / 256, k = u % 256;
        Wtn[u] = (__bf16)(Wn[(size_t)k * 128 + j] + ((k == j) ? 1.0f : 0.0f));
    }
}

// ---------------------------------------------------------------------------
// Edge update via MFMA, async-staged (R11/R13 schedule — 3.6-3.8 TB/s):
//  - double-buffered LDS, ONE __syncthreads per K-step
//  - staging via global_load_lds w=16, XOR-pre-swizzled global source
//  - fused degree count (atomics issued AFTER first stage -> overlapped)
//  - residual folded into Wt; epilogue = bias + LN + f32 & bf16-shadow store
// ---------------------------------------------------------------------------
#define ESTAGE(b, kt) { \
    _Pragma("unroll") \
    for (int r = 0; r < 4; ++r) { \
        const float* g = ((kt) < 4) ? baseE[r] + (kt) * 32 \
                       : ((kt) < 8) ? baseS[r] + ((kt) - 4) * 32 \
                                    : baseT[r] + ((kt) - 8) * 32; \
        GLOAD16(g, &Asf[b][(wid * 4 + r) * 256]); \
    } \
    _Pragma("unroll") \
    for (int r = 0; r < 2; ++r) \
        GLOAD16(baseW[r] + (kt) * 32, &Btf[b][(wid * 2 + r) * 512]); }

#define EFRAG_MFMA(b) { \
    bf16x8 afm[2]; \
    _Pragma("unroll") \
    for (int mt = 0; mt < 2; ++mt) { \
        const int row = wid * 32 + mt * 16 + li; \
        const int swz = li & 7; \
        const f32x4 va = *(const f32x4*)&Asf[b][row * 32 + (((lg * 2) ^ swz) << 2)]; \
        const f32x4 vb = *(const f32x4*)&Asf[b][row * 32 + (((lg * 2 + 1) ^ swz) << 2)]; \
        bf16x8 af; \
        af[0] = (__bf16)va[0]; af[1] = (__bf16)va[1]; \
        af[2] = (__bf16)va[2]; af[3] = (__bf16)va[3]; \
        af[4] = (__bf16)vb[0]; af[5] = (__bf16)vb[1]; \
        af[6] = (__bf16)vb[2]; af[7] = (__bf16)vb[3]; \
        afm[mt] = af; \
    } \
    _Pragma("unroll") \
    for (int nt = 0; nt < 8; ++nt) { \
        const int col = nt * 16 + li; \
        const bf16x8 bfr = \
            *(const bf16x8*)&Btf[b][col * 32 + ((lg ^ ((li >> 1) & 3)) << 3)]; \
        acc[0][nt] = __builtin_amdgcn_mfma_f32_16x16x32_bf16(afm[0], bfr, acc[0][nt], 0, 0, 0); \
        acc[1][nt] = __builtin_amdgcn_mfma_f32_16x16x32_bf16(afm[1], bfr, acc[1][nt], 0, 0, 0); \
    } }

__launch_bounds__(256)
__global__ void edge_kernel(const float* __restrict__ nodef,
                            const float* __restrict__ edgef,
                            const int*   __restrict__ eidx,
                            const __bf16* __restrict__ Wt,
                            const float* __restrict__ be,
                            const float* __restrict__ gamma_e,
                            const float* __restrict__ beta_e,
                            float* __restrict__ new_edges,
                            __bf16* __restrict__ sh,
                            int* __restrict__ cnt)
{
    __shared__ float  Asf[2][4096];   // [buf][row*32 + chunk-swizzled k] f32
    __shared__ __bf16 Btf[2][4096];   // [buf][col*32 + chunk-swizzled k] bf16
    __shared__ int s_src[128], s_tgt[128];

    const int tid = threadIdx.x;
    const int e0  = blockIdx.x * 128;

    if (tid < 128) {
        s_src[tid] = eidx[min(e0 + tid, N_EDGES - 1)];
    } else {
        s_tgt[tid - 128] = eidx[N_EDGES + min(e0 + tid - 128, N_EDGES - 1)];
    }
    __syncthreads();   // idx ready

    const int wid  = tid >> 6;
    const int lane = tid & 63;
    const int li   = lane & 15;
    const int lg   = lane >> 4;

    // per-thread pre-swizzled global base pointers (kt-independent)
    const float* baseE[4];
    const float* baseS[4];
    const float* baseT[4];
    #pragma unroll
    for (int r = 0; r < 4; ++r) {
        const int idx = (wid * 4 + r) * 64 + lane;    // flat 16B-chunk id
        const int row = idx >> 3;
        const int ch  = idx & 7;
        const int cg  = ch ^ (row & 7);
        const int er  = min(e0 + row, N_EDGES - 1);
        baseE[r] = edgef + (size_t)er * D + cg * 4;
        baseS[r] = nodef + (size_t)s_src[row] * D + cg * 4;
        baseT[r] = nodef + (size_t)s_tgt[row] * D + cg * 4;
    }
    const __bf16* baseW[2];
    #pragma unroll
    for (int r = 0; r < 2; ++r) {
        const int idx = (wid * 2 + r) * 64 + lane;
        const int col = idx >> 2;
        const int ch  = idx & 3;
        const int cg  = ch ^ ((col >> 1) & 3);
        baseW[r] = Wt + (size_t)col * 384 + cg * 8;
    }

    f32x4 acc[2][8];
    const f32x4 zero = {0.f, 0.f, 0.f, 0.f};
    #pragma unroll
    for (int m = 0; m < 2; ++m)
        #pragma unroll
        for (int n = 0; n < 8; ++n) acc[m][n] = zero;

    ESTAGE(0, 0);
    // fused degree count — issued after stage(0), overlaps its latency
    if (tid < 128) {
        if (e0 + tid < N_EDGES) atomicAdd(&cnt[s_src[tid]], 1);
    } else {
        if (e0 + tid - 128 < N_EDGES) atomicAdd(&cnt[s_tgt[tid - 128]], 1);
    }
    __syncthreads();                      // drain prologue loads
    #pragma unroll
    for (int kt = 0; kt < 12; ++kt) {
        const int b = kt & 1;
        if (kt < 11) ESTAGE(b ^ 1, kt + 1);   // async, in flight over MFMAs
        EFRAG_MFMA(b);
        if (kt < 11) __syncthreads();         // drains next-tile loads too
    }

    // ---- epilogue: bias + LN + store (+ bf16 shadow); residual is in Wt ----
    float g[8], bt_[8], bias[8];
    #pragma unroll
    for (int nt = 0; nt < 8; ++nt) {
        const int col = nt * 16 + li;
        g[nt]    = gamma_e[col];
        bt_[nt]  = beta_e[col];
        bias[nt] = be[col];
    }

    #pragma unroll
    for (int mt = 0; mt < 2; ++mt) {
        #pragma unroll
        for (int r = 0; r < 4; ++r) {
            const int rl = wid * 32 + mt * 16 + lg * 4 + r;
            const int e  = e0 + rl;
            float x[8];
            float s = 0.f;
            #pragma unroll
            for (int nt = 0; nt < 8; ++nt) {
                x[nt] = acc[mt][nt][r] + bias[nt];
                s += x[nt];
            }
            ROWRED(s);
            const float mean = s * 0.0078125f;
            float vs = 0.f;
            #pragma unroll
            for (int nt = 0; nt < 8; ++nt) { const float d_ = x[nt] - mean; vs = fmaf(d_, d_, vs); }
            ROWRED(vs);
            const float rstd = rsqrtf(vs * 0.0078125f + LN_EPS);
            if (e < N_EDGES) {
                const size_t ec = (size_t)e;
                float y[8];
                #pragma unroll
                for (int nt = 0; nt < 8; ++nt)
                    y[nt] = fmaf((x[nt] - mean) * rstd, g[nt], bt_[nt]);
                #pragma unroll
                for (int nt = 0; nt < 8; ++nt)
                    new_edges[ec * D + nt * 16 + li] = y[nt];
                if (sh) {
                    #pragma unroll
                    for (int nt = 0; nt < 8; ++nt)
                        sh[ec * D + nt * 16 + li] = (__bf16)y[nt];
                }
            }
        }
    }
}

// ---------------------------------------------------------------------------
// Node update via MFMA, async-staged (same pattern; A rows are contiguous).
// Residual folded into Wtn; epilogue = bias + LN only.
// ---------------------------------------------------------------------------
#define NSTAGE(b, kt) { \
    _Pragma("unroll") \
    for (int r = 0; r < 4; ++r) { \
        const float* g = ((kt) < 4) ? baseN[r] + (kt) * 32 \
                                    : baseM[r] + ((kt) - 4) * 32; \
        GLOAD16(g, &Asf[b][(wid * 4 + r) * 256]); \
    } \
    _Pragma("unroll") \
    for (int r = 0; r < 2; ++r) \
        GLOAD16(baseW[r] + (kt) * 32, &Btf[b][(wid * 2 + r) * 512]); }

__launch_bounds__(256)
__global__ void node_kernel(const float* __restrict__ nodef,
                            const __bf16* __restrict__ Wtn,
                            const float* __restrict__ bn,
                            const float* __restrict__ gamma_n,
                            const float* __restrict__ beta_n,
                            const float* __restrict__ edge_mean,
                            float* __restrict__ new_nodes)
{
    __shared__ float  Asf[2][4096];
    __shared__ __bf16 Btf[2][4096];

    const int tid = threadIdx.x;
    const int n0  = blockIdx.x * 128;

    const int wid  = tid >> 6;
    const int lane = tid & 63;
    const int li   = lane & 15;
    const int lg   = lane >> 4;

    const float* baseN[4];
    const float* baseM[4];
    #pragma unroll
    for (int r = 0; r < 4; ++r) {
        const int idx = (wid * 4 + r) * 64 + lane;
        const int row = idx >> 3;
        const int ch  = idx & 7;
        const int cg  = ch ^ (row & 7);
        const size_t nr = (size_t)min(n0 + row, N_NODES - 1);
        baseN[r] = nodef     + nr * D + cg * 4;
        baseM[r] = edge_mean + nr * D + cg * 4;
    }
    const __bf16* baseW[2];
    #pragma unroll
    for (int r = 0; r < 2; ++r) {
        const int idx = (wid * 2 + r) * 64 + lane;
        const int col = idx >> 2;
        const int ch  = idx & 3;
        const int cg  = ch ^ ((col >> 1) & 3);
        baseW[r] = Wtn + (size_t)col * 256 + cg * 8;
    }

    f32x4 acc[2][8];
    const f32x4 zero = {0.f, 0.f, 0.f, 0.f};
    #pragma unroll
    for (int m = 0; m < 2; ++m)
        #pragma unroll
        for (int n = 0; n < 8; ++n) acc[m][n] = zero;

    NSTAGE(0, 0);
    __syncthreads();
    #pragma unroll
    for (int kt = 0; kt < 8; ++kt) {
        const int b = kt & 1;
        if (kt < 7) NSTAGE(b ^ 1, kt + 1);
        EFRAG_MFMA(b);
        if (kt < 7) __syncthreads();
    }

    float g[8], bt_[8], bias[8];
    #pragma unroll
    for (int nt = 0; nt < 8; ++nt) {
        const int col = nt * 16 + li;
        g[nt]    = gamma_n[col];
        bt_[nt]  = beta_n[col];
        bias[nt] = bn[col];
    }

    #pragma unroll
    for (int mt = 0; mt < 2; ++mt) {
        #pragma unroll
        for (int r = 0; r < 4; ++r) {
            const int rl = wid * 32 + mt * 16 + lg * 4 + r;
            const int n  = n0 + rl;
            float x[8];
            float s = 0.f;
            #pragma unroll
            for (int nt = 0; nt < 8; ++nt) {
                x[nt] = acc[mt][nt][r] + bias[nt];
                s += x[nt];
            }
            ROWRED(s);
            const float mean = s * 0.0078125f;
            float vs = 0.f;
            #pragma unroll
            for (int nt = 0; nt < 8; ++nt) { const float d_ = x[nt] - mean; vs = fmaf(d_, d_, vs); }
            ROWRED(vs);
            const float rstd = rsqrtf(vs * 0.0078125f + LN_EPS);
            if (n < N_NODES) {
                #pragma unroll
                for (int nt = 0; nt < 8; ++nt)
                    new_nodes[(size_t)n * D + nt * 16 + li] =
                        fmaf((x[nt] - mean) * rstd, g[nt], bt_[nt]);
            }
        }
    }
}

// ---------------------------------------------------------------------------
// CSR build: (count fused in edge_kernel) -> scan1 -> scan2 -> fill
// (scan3 eliminated: fill/aggregate compute positions from excl+bsum)
// ---------------------------------------------------------------------------
__global__ void scan1(const int* __restrict__ cnt, int* __restrict__ excl,
                      int* __restrict__ bsum)
{
    const int tid = threadIdx.x, lane = tid & 63, wid = tid >> 6;
    const int i = blockIdx.x * 256 + tid;
    const int v = (i < N_NODES) ? cnt[i] : 0;
    int x = v;
    #pragma unroll
    for (int s = 1; s < 64; s <<= 1) { const int t = __shfl_up(x, s); if (lane >= s) x += t; }
    __shared__ int ws[4], wb[4];
    if (lane == 63) ws[wid] = x;
    __syncthreads();
    if (tid == 0) {
        int run = 0;
        #pragma unroll
        for (int w = 0; w < 4; ++w) { wb[w] = run; run += ws[w]; }
        bsum[blockIdx.x] = run;
    }
    __syncthreads();
    if (i < N_NODES) excl[i] = wb[wid] + x - v;
}

__global__ void scan2(int* __restrict__ bsum)
{
    __shared__ int ws[4], wb[4];
    __shared__ int sbase;
    const int tid = threadIdx.x, lane = tid & 63, wid = tid >> 6;
    if (tid == 0) sbase = 0;
    __syncthreads();
    for (int chunk = 0; chunk < NB; chunk += 256) {
        const int i = chunk + tid;
        const int v = (i < NB) ? bsum[i] : 0;
        int x = v;
        #pragma unroll
        for (int s = 1; s < 64; s <<= 1) { const int t = __shfl_up(x, s); if (lane >= s) x += t; }
        if (lane == 63) ws[wid] = x;
        __syncthreads();
        if (tid == 0) {
            int run = sbase;
            #pragma unroll
            for (int w = 0; w < 4; ++w) { wb[w] = run; run += ws[w]; }
            sbase = run;
        }
        __syncthreads();
        if (i < NB) bsum[i] = wb[wid] + x - v;
        __syncthreads();
    }
}

__global__ void fill_kernel(const int* __restrict__ eidx,
                            const int* __restrict__ excl,
                            const int* __restrict__ bsum,
                            int* __restrict__ ctr,
                            int* __restrict__ list)
{
    const int i = blockIdx.x * blockDim.x + threadIdx.x;
    if (i < 2 * N_EDGES) {
        const int n   = eidx[i];
        const int pos = excl[n] + bsum[n >> 8] + atomicAdd(&ctr[n], 1);
        list[pos] = (i < N_EDGES) ? i : i - N_EDGES;
    }
}

// ---------------------------------------------------------------------------
// Aggregation: one wave per node, unroll-8. Bounds from excl+bsum+cnt.
// ---------------------------------------------------------------------------
template<bool SH>
__launch_bounds__(256)
__global__ void aggregate_kernel(const float* __restrict__ nef,
                                 const __bf16* __restrict__ sh,
                                 const int* __restrict__ excl,
                                 const int* __restrict__ bsum,
                                 const int* __restrict__ cnt,
                                 const int* __restrict__ list,
                                 float* __restrict__ edge_mean)
{
    const int lane   = threadIdx.x & 63;
    const int gwave  = (blockIdx.x * 256 + threadIdx.x) >> 6;
    const int nwaves = gridDim.x * 4;

    for (int n = gwave; n < N_NODES; n += nwaves) {
        const int beg = excl[n] + bsum[n >> 8];
        const int deg = cnt[n];
        const int end = beg + deg;
        float ax0 = 0.f, ay0 = 0.f, ax1 = 0.f, ay1 = 0.f;
        float ax2 = 0.f, ay2 = 0.f, ax3 = 0.f, ay3 = 0.f;
        int j = beg;
        if (SH) {
            const unsigned int* base = (const unsigned int*)sh;
            for (; j + 8 <= end; j += 8) {
                unsigned int u[8];
                #pragma unroll
                for (int q = 0; q < 8; ++q)
                    u[q] = base[(size_t)list[j + q] * 64 + lane];
                ax0 += __uint_as_float(u[0] << 16) + __uint_as_float(u[4] << 16);
                ay0 += __uint_as_float(u[0] & 0xffff0000u) + __uint_as_float(u[4] & 0xffff0000u);
                ax1 += __uint_as_float(u[1] << 16) + __uint_as_float(u[5] << 16);
                ay1 += __uint_as_float(u[1] & 0xffff0000u) + __uint_as_float(u[5] & 0xffff0000u);
                ax2 += __uint_as_float(u[2] << 16) + __uint_as_float(u[6] << 16);
                ay2 += __uint_as_float(u[2] & 0xffff0000u) + __uint_as_float(u[6] & 0xffff0000u);
                ax3 += __uint_as_float(u[3] << 16) + __uint_as_float(u[7] << 16);
                ay3 += __uint_as_float(u[3] & 0xffff0000u) + __uint_as_float(u[7] & 0xffff0000u);
            }
            for (; j < end; ++j) {
                const unsigned int u = base[(size_t)list[j] * 64 + lane];
                ax0 += __uint_as_float(u << 16); ay0 += __uint_as_float(u & 0xffff0000u);
            }
        } else {
            for (; j + 4 <= end; j += 4) {
                const int e0 = list[j], e1 = list[j + 1], e2 = list[j + 2], e3 = list[j + 3];
                const float2 w0 = ((const float2*)(nef + (size_t)e0 * D))[lane];
                const float2 w1 = ((const float2*)(nef + (size_t)e1 * D))[lane];
                const float2 w2 = ((const float2*)(nef + (size_t)e2 * D))[lane];
                const float2 w3 = ((const float2*)(nef + (size_t)e3 * D))[lane];
                ax0 += w0.x; ay0 += w0.y; ax1 += w1.x; ay1 += w1.y;
                ax2 += w2.x; ay2 += w2.y; ax3 += w3.x; ay3 += w3.y;
            }
            for (; j < end; ++j) {
                const float2 w = ((const float2*)(nef + (size_t)list[j] * D))[lane];
                ax0 += w.x; ay0 += w.y;
            }
        }
        const float sx = (ax0 + ax1) + (ax2 + ax3);
        const float sy = (ay0 + ay1) + (ay2 + ay3);
        const float inv = 1.0f / ((float)deg + CNT_EPS);
        ((float2*)(edge_mean + (size_t)n * D))[lane] = make_float2(sx * inv, sy * inv);
    }
}

extern "C" void kernel_launch(void* const* d_in, const int* in_sizes, int n_in,
                              void* d_out, int out_size, void* d_ws, size_t ws_size,
                              hipStream_t stream) {
    const float* nodef   = (const float*)d_in[0];
    const float* edgef   = (const float*)d_in[1];
    const int*   eidx    = (const int*)d_in[2];
    const float* We      = (const float*)d_in[3];
    const float* be      = (const float*)d_in[4];
    const float* gamma_e = (const float*)d_in[5];
    const float* beta_e  = (const float*)d_in[6];
    const float* Wn      = (const float*)d_in[7];
    const float* bn      = (const float*)d_in[8];
    const float* gamma_n = (const float*)d_in[9];
    const float* beta_n  = (const float*)d_in[10];

    float* new_nodes = (float*)d_out;                      // also edge_mean buffer
    float* new_edges = (float*)d_out + (size_t)N_NODES * D;

    // workspace layout
    char* p = (char*)d_ws;
    __bf16* Wt  = (__bf16*)p;  p += 128 * 384 * 2;     // 98304
    __bf16* Wtn = (__bf16*)p;  p += 128 * 256 * 2;     // 65536
    int* cnt    = (int*)p;     p += (size_t)N_NODES * 4;
    int* excl   = (int*)p;     p += (size_t)N_NODES * 4;
    int* ctr    = (int*)p;     p += (size_t)N_NODES * 4;
    int* bsum   = (int*)p;     p += 2048;
    int* list   = (int*)p;     p += (size_t)2 * N_EDGES * 4;
    const size_t base_bytes = (size_t)(p - (char*)d_ws);
    const size_t shadow_bytes = (size_t)N_EDGES * D * 2;
    __bf16* shadow = nullptr;
    if (ws_size >= base_bytes + shadow_bytes) shadow = (__bf16*)p;

    hipMemsetAsync(cnt, 0, (size_t)N_NODES * sizeof(int), stream);
    hipMemsetAsync(ctr, 0, (size_t)N_NODES * sizeof(int), stream);

    prep_w<<<320, 256, 0, stream>>>(We, Wn, Wt, Wtn);

    edge_kernel<<<(N_EDGES + 127) / 128, 256, 0, stream>>>(
        nodef, edgef, eidx, Wt, be, gamma_e, beta_e, new_edges, shadow, cnt);

    scan1<<<NB, 256, 0, stream>>>(cnt, excl, bsum);
    scan2<<<1, 256, 0, stream>>>(bsum);
    fill_kernel<<<(2 * N_EDGES + 255) / 256, 256, 0, stream>>>(eidx, excl, bsum, ctr, list);

    if (shadow)
        aggregate_kernel<true><<<2048, 256, 0, stream>>>(new_edges, shadow, excl, bsum, cnt, list, new_nodes);
    else
        aggregate_kernel<false><<<2048, 256, 0, stream>>>(new_edges, nullptr, excl, bsum, cnt, list, new_nodes);

    node_kernel<<<(N_NODES + 127) / 128, 256, 0, stream>>>(
        nodef, Wtn, bn, gamma_n, beta_n, new_nodes, new_nodes);
}

// Round 16
// 657.120 us; speedup vs baseline: 1.5897x; 1.0204x over previous
//
#include <hip/hip_runtime.h>

#define N_NODES 100000
#define N_EDGES 1000000
#define D 128
#define NB ((N_NODES + 255) / 256)   // 391 scan blocks
#define LN_EPS 1e-5f
#define CNT_EPS 1e-10f

typedef __bf16 bf16x8 __attribute__((ext_vector_type(8)));
typedef __bf16 bf16x4 __attribute__((ext_vector_type(4)));
typedef float  f32x4  __attribute__((ext_vector_type(4)));

#define ROWRED(v) { v += __shfl_xor(v, 1); v += __shfl_xor(v, 2); \
                    v += __shfl_xor(v, 4); v += __shfl_xor(v, 8); }

// async 16B global->LDS; LDS dest is wave-uniform base + lane*16 (m104/m108)
#define GLOAD16(g, l) \
    __builtin_amdgcn_global_load_lds( \
        (const __attribute__((address_space(1))) void*)(g), \
        (__attribute__((address_space(3))) void*)(l), 16, 0, 0)

// ---------------------------------------------------------------------------
// Prep: Wt[j][k]  = bf16(We[k][j] + (k==j))   (128x384, residual folded in)
//       Wtn[j][k] = bf16(Wn[k][j] + (k==j))   (128x256, residual folded in)
// ---------------------------------------------------------------------------
__global__ void prep_w(const float* __restrict__ We, const float* __restrict__ Wn,
                       __bf16* __restrict__ Wt, __bf16* __restrict__ Wtn)
{
    const int t = blockIdx.x * 256 + threadIdx.x;
    if (t < 128 * 384) {
        const int j = t / 384, k = t % 384;
        Wt[t] = (__bf16)(We[(size_t)k * 128 + j] + ((k == j) ? 1.0f : 0.0f));
    } else if (t < 128 * 384 + 128 * 256) {
        const int u = t - 128 * 384;
        const int j = u / 256, k = u % 256;
        Wtn[u] = (__bf16)(Wn[(size_t)k * 128 + j] + ((k == j) ? 1.0f : 0.0f));
    }
}

// ---------------------------------------------------------------------------
// Edge update via MFMA, async-staged (R11/R13 schedule — 3.7 TB/s):
//  - double-buffered LDS, ONE __syncthreads per K-step
//  - staging via global_load_lds w=16, XOR-pre-swizzled global source
//  - fused degree count (atomics issued after first stage -> overlapped)
//  - residual folded into Wt; nontemporal f32 output stores (never re-read)
// ---------------------------------------------------------------------------
#define ESTAGE(b, kt) { \
    _Pragma("unroll") \
    for (int r = 0; r < 4; ++r) { \
        const float* g = ((kt) < 4) ? baseE[r] + (kt) * 32 \
                       : ((kt) < 8) ? baseS[r] + ((kt) - 4) * 32 \
                                    : baseT[r] + ((kt) - 8) * 32; \
        GLOAD16(g, &Asf[b][(wid * 4 + r) * 256]); \
    } \
    _Pragma("unroll") \
    for (int r = 0; r < 2; ++r) \
        GLOAD16(baseW[r] + (kt) * 32, &Btf[b][(wid * 2 + r) * 512]); }

#define EFRAG_MFMA(b) { \
    bf16x8 afm[2]; \
    _Pragma("unroll") \
    for (int mt = 0; mt < 2; ++mt) { \
        const int row = wid * 32 + mt * 16 + li; \
        const int swz = li & 7; \
        const f32x4 va = *(const f32x4*)&Asf[b][row * 32 + (((lg * 2) ^ swz) << 2)]; \
        const f32x4 vb = *(const f32x4*)&Asf[b][row * 32 + (((lg * 2 + 1) ^ swz) << 2)]; \
        bf16x8 af; \
        af[0] = (__bf16)va[0]; af[1] = (__bf16)va[1]; \
        af[2] = (__bf16)va[2]; af[3] = (__bf16)va[3]; \
        af[4] = (__bf16)vb[0]; af[5] = (__bf16)vb[1]; \
        af[6] = (__bf16)vb[2]; af[7] = (__bf16)vb[3]; \
        afm[mt] = af; \
    } \
    _Pragma("unroll") \
    for (int nt = 0; nt < 8; ++nt) { \
        const int col = nt * 16 + li; \
        const bf16x8 bfr = \
            *(const bf16x8*)&Btf[b][col * 32 + ((lg ^ ((li >> 1) & 3)) << 3)]; \
        acc[0][nt] = __builtin_amdgcn_mfma_f32_16x16x32_bf16(afm[0], bfr, acc[0][nt], 0, 0, 0); \
        acc[1][nt] = __builtin_amdgcn_mfma_f32_16x16x32_bf16(afm[1], bfr, acc[1][nt], 0, 0, 0); \
    } }

__launch_bounds__(256)
__global__ void edge_kernel(const float* __restrict__ nodef,
                            const float* __restrict__ edgef,
                            const int*   __restrict__ eidx,
                            const __bf16* __restrict__ Wt,
                            const float* __restrict__ be,
                            const float* __restrict__ gamma_e,
                            const float* __restrict__ beta_e,
                            float* __restrict__ new_edges,
                            __bf16* __restrict__ sh,
                            int* __restrict__ cnt)
{
    __shared__ float  Asf[2][4096];   // [buf][row*32 + chunk-swizzled k] f32
    __shared__ __bf16 Btf[2][4096];   // [buf][col*32 + chunk-swizzled k] bf16
    __shared__ int s_src[128], s_tgt[128];

    const int tid = threadIdx.x;
    const int e0  = blockIdx.x * 128;

    if (tid < 128) {
        s_src[tid] = eidx[min(e0 + tid, N_EDGES - 1)];
    } else {
        s_tgt[tid - 128] = eidx[N_EDGES + min(e0 + tid - 128, N_EDGES - 1)];
    }
    __syncthreads();   // idx ready

    const int wid  = tid >> 6;
    const int lane = tid & 63;
    const int li   = lane & 15;
    const int lg   = lane >> 4;

    // per-thread pre-swizzled global base pointers (kt-independent)
    const float* baseE[4];
    const float* baseS[4];
    const float* baseT[4];
    #pragma unroll
    for (int r = 0; r < 4; ++r) {
        const int idx = (wid * 4 + r) * 64 + lane;    // flat 16B-chunk id
        const int row = idx >> 3;
        const int ch  = idx & 7;
        const int cg  = ch ^ (row & 7);
        const int er  = min(e0 + row, N_EDGES - 1);
        baseE[r] = edgef + (size_t)er * D + cg * 4;
        baseS[r] = nodef + (size_t)s_src[row] * D + cg * 4;
        baseT[r] = nodef + (size_t)s_tgt[row] * D + cg * 4;
    }
    const __bf16* baseW[2];
    #pragma unroll
    for (int r = 0; r < 2; ++r) {
        const int idx = (wid * 2 + r) * 64 + lane;
        const int col = idx >> 2;
        const int ch  = idx & 3;
        const int cg  = ch ^ ((col >> 1) & 3);
        baseW[r] = Wt + (size_t)col * 384 + cg * 8;
    }

    f32x4 acc[2][8];
    const f32x4 zero = {0.f, 0.f, 0.f, 0.f};
    #pragma unroll
    for (int m = 0; m < 2; ++m)
        #pragma unroll
        for (int n = 0; n < 8; ++n) acc[m][n] = zero;

    ESTAGE(0, 0);
    // fused degree count — issued after stage(0), overlaps its latency
    if (tid < 128) {
        if (e0 + tid < N_EDGES) atomicAdd(&cnt[s_src[tid]], 1);
    } else {
        if (e0 + tid - 128 < N_EDGES) atomicAdd(&cnt[s_tgt[tid - 128]], 1);
    }
    __syncthreads();                      // drain prologue loads
    #pragma unroll
    for (int kt = 0; kt < 12; ++kt) {
        const int b = kt & 1;
        if (kt < 11) ESTAGE(b ^ 1, kt + 1);   // async, in flight over MFMAs
        EFRAG_MFMA(b);
        if (kt < 11) __syncthreads();         // drains next-tile loads too
    }

    // ---- epilogue: bias + LN + store (+ bf16 shadow); residual is in Wt ----
    float g[8], bt_[8], bias[8];
    #pragma unroll
    for (int nt = 0; nt < 8; ++nt) {
        const int col = nt * 16 + li;
        g[nt]    = gamma_e[col];
        bt_[nt]  = beta_e[col];
        bias[nt] = be[col];
    }

    #pragma unroll
    for (int mt = 0; mt < 2; ++mt) {
        #pragma unroll
        for (int r = 0; r < 4; ++r) {
            const int rl = wid * 32 + mt * 16 + lg * 4 + r;
            const int e  = e0 + rl;
            float x[8];
            float s = 0.f;
            #pragma unroll
            for (int nt = 0; nt < 8; ++nt) {
                x[nt] = acc[mt][nt][r] + bias[nt];
                s += x[nt];
            }
            ROWRED(s);
            const float mean = s * 0.0078125f;
            float vs = 0.f;
            #pragma unroll
            for (int nt = 0; nt < 8; ++nt) { const float d_ = x[nt] - mean; vs = fmaf(d_, d_, vs); }
            ROWRED(vs);
            const float rstd = rsqrtf(vs * 0.0078125f + LN_EPS);
            if (e < N_EDGES) {
                const size_t ec = (size_t)e;
                float y[8];
                #pragma unroll
                for (int nt = 0; nt < 8; ++nt)
                    y[nt] = fmaf((x[nt] - mean) * rstd, g[nt], bt_[nt]);
                #pragma unroll
                for (int nt = 0; nt < 8; ++nt)
                    __builtin_nontemporal_store(y[nt], &new_edges[ec * D + nt * 16 + li]);
                if (sh) {
                    #pragma unroll
                    for (int nt = 0; nt < 8; ++nt)
                        sh[ec * D + nt * 16 + li] = (__bf16)y[nt];
                }
            }
        }
    }
}

// ---------------------------------------------------------------------------
// Node update via MFMA, async-staged (same pattern; A rows are contiguous).
// Residual folded into Wtn; epilogue = bias + LN only.
// ---------------------------------------------------------------------------
#define NSTAGE(b, kt) { \
    _Pragma("unroll") \
    for (int r = 0; r < 4; ++r) { \
        const float* g = ((kt) < 4) ? baseN[r] + (kt) * 32 \
                                    : baseM[r] + ((kt) - 4) * 32; \
        GLOAD16(g, &Asf[b][(wid * 4 + r) * 256]); \
    } \
    _Pragma("unroll") \
    for (int r = 0; r < 2; ++r) \
        GLOAD16(baseW[r] + (kt) * 32, &Btf[b][(wid * 2 + r) * 512]); }

__launch_bounds__(256)
__global__ void node_kernel(const float* __restrict__ nodef,
                            const __bf16* __restrict__ Wtn,
                            const float* __restrict__ bn,
                            const float* __restrict__ gamma_n,
                            const float* __restrict__ beta_n,
                            const float* __restrict__ edge_mean,
                            float* __restrict__ new_nodes)
{
    __shared__ float  Asf[2][4096];
    __shared__ __bf16 Btf[2][4096];

    const int tid = threadIdx.x;
    const int n0  = blockIdx.x * 128;

    const int wid  = tid >> 6;
    const int lane = tid & 63;
    const int li   = lane & 15;
    const int lg   = lane >> 4;

    const float* baseN[4];
    const float* baseM[4];
    #pragma unroll
    for (int r = 0; r < 4; ++r) {
        const int idx = (wid * 4 + r) * 64 + lane;
        const int row = idx >> 3;
        const int ch  = idx & 7;
        const int cg  = ch ^ (row & 7);
        const size_t nr = (size_t)min(n0 + row, N_NODES - 1);
        baseN[r] = nodef     + nr * D + cg * 4;
        baseM[r] = edge_mean + nr * D + cg * 4;
    }
    const __bf16* baseW[2];
    #pragma unroll
    for (int r = 0; r < 2; ++r) {
        const int idx = (wid * 2 + r) * 64 + lane;
        const int col = idx >> 2;
        const int ch  = idx & 3;
        const int cg  = ch ^ ((col >> 1) & 3);
        baseW[r] = Wtn + (size_t)col * 256 + cg * 8;
    }

    f32x4 acc[2][8];
    const f32x4 zero = {0.f, 0.f, 0.f, 0.f};
    #pragma unroll
    for (int m = 0; m < 2; ++m)
        #pragma unroll
        for (int n = 0; n < 8; ++n) acc[m][n] = zero;

    NSTAGE(0, 0);
    __syncthreads();
    #pragma unroll
    for (int kt = 0; kt < 8; ++kt) {
        const int b = kt & 1;
        if (kt < 7) NSTAGE(b ^ 1, kt + 1);
        EFRAG_MFMA(b);
        if (kt < 7) __syncthreads();
    }

    float g[8], bt_[8], bias[8];
    #pragma unroll
    for (int nt = 0; nt < 8; ++nt) {
        const int col = nt * 16 + li;
        g[nt]    = gamma_n[col];
        bt_[nt]  = beta_n[col];
        bias[nt] = bn[col];
    }

    #pragma unroll
    for (int mt = 0; mt < 2; ++mt) {
        #pragma unroll
        for (int r = 0; r < 4; ++r) {
            const int rl = wid * 32 + mt * 16 + lg * 4 + r;
            const int n  = n0 + rl;
            float x[8];
            float s = 0.f;
            #pragma unroll
            for (int nt = 0; nt < 8; ++nt) {
                x[nt] = acc[mt][nt][r] + bias[nt];
                s += x[nt];
            }
            ROWRED(s);
            const float mean = s * 0.0078125f;
            float vs = 0.f;
            #pragma unroll
            for (int nt = 0; nt < 8; ++nt) { const float d_ = x[nt] - mean; vs = fmaf(d_, d_, vs); }
            ROWRED(vs);
            const float rstd = rsqrtf(vs * 0.0078125f + LN_EPS);
            if (n < N_NODES) {
                #pragma unroll
                for (int nt = 0; nt < 8; ++nt)
                    new_nodes[(size_t)n * D + nt * 16 + li] =
                        fmaf((x[nt] - mean) * rstd, g[nt], bt_[nt]);
            }
        }
    }
}

// ---------------------------------------------------------------------------
// CSR build: (count fused in edge_kernel) -> scan1 -> scan2 -> fill
// ---------------------------------------------------------------------------
__global__ void scan1(const int* __restrict__ cnt, int* __restrict__ excl,
                      int* __restrict__ bsum)
{
    const int tid = threadIdx.x, lane = tid & 63, wid = tid >> 6;
    const int i = blockIdx.x * 256 + tid;
    const int v = (i < N_NODES) ? cnt[i] : 0;
    int x = v;
    #pragma unroll
    for (int s = 1; s < 64; s <<= 1) { const int t = __shfl_up(x, s); if (lane >= s) x += t; }
    __shared__ int ws[4], wb[4];
    if (lane == 63) ws[wid] = x;
    __syncthreads();
    if (tid == 0) {
        int run = 0;
        #pragma unroll
        for (int w = 0; w < 4; ++w) { wb[w] = run; run += ws[w]; }
        bsum[blockIdx.x] = run;
    }
    __syncthreads();
    if (i < N_NODES) excl[i] = wb[wid] + x - v;
}

__global__ void scan2(int* __restrict__ bsum)
{
    __shared__ int ws[4], wb[4];
    __shared__ int sbase;
    const int tid = threadIdx.x, lane = tid & 63, wid = tid >> 6;
    if (tid == 0) sbase = 0;
    __syncthreads();
    for (int chunk = 0; chunk < NB; chunk += 256) {
        const int i = chunk + tid;
        const int v = (i < NB) ? bsum[i] : 0;
        int x = v;
        #pragma unroll
        for (int s = 1; s < 64; s <<= 1) { const int t = __shfl_up(x, s); if (lane >= s) x += t; }
        if (lane == 63) ws[wid] = x;
        __syncthreads();
        if (tid == 0) {
            int run = sbase;
            #pragma unroll
            for (int w = 0; w < 4; ++w) { wb[w] = run; run += ws[w]; }
            sbase = run;
        }
        __syncthreads();
        if (i < NB) bsum[i] = wb[wid] + x - v;
        __syncthreads();
    }
}

// one thread per EDGE: both endpoints, 2 independent atomics in flight
__global__ void fill_kernel(const int* __restrict__ eidx,
                            const int* __restrict__ excl,
                            const int* __restrict__ bsum,
                            int* __restrict__ ctr,
                            int* __restrict__ list)
{
    const int i = blockIdx.x * blockDim.x + threadIdx.x;
    if (i < N_EDGES) {
        const int n1 = eidx[i];
        const int n2 = eidx[N_EDGES + i];
        const int p1 = excl[n1] + bsum[n1 >> 8] + atomicAdd(&ctr[n1], 1);
        const int p2 = excl[n2] + bsum[n2 >> 8] + atomicAdd(&ctr[n2], 1);
        list[p1] = i;
        list[p2] = i;
    }
}

// ---------------------------------------------------------------------------
// Aggregation: one wave per node, unroll-8, 4096 blocks (2x TLP).
// ---------------------------------------------------------------------------
template<bool SH>
__launch_bounds__(256)
__global__ void aggregate_kernel(const float* __restrict__ nef,
                                 const __bf16* __restrict__ sh,
                                 const int* __restrict__ excl,
                                 const int* __restrict__ bsum,
                                 const int* __restrict__ cnt,
                                 const int* __restrict__ list,
                                 float* __restrict__ edge_mean)
{
    const int lane   = threadIdx.x & 63;
    const int gwave  = (blockIdx.x * 256 + threadIdx.x) >> 6;
    const int nwaves = gridDim.x * 4;

    for (int n = gwave; n < N_NODES; n += nwaves) {
        const int beg = excl[n] + bsum[n >> 8];
        const int deg = cnt[n];
        const int end = beg + deg;
        float ax0 = 0.f, ay0 = 0.f, ax1 = 0.f, ay1 = 0.f;
        float ax2 = 0.f, ay2 = 0.f, ax3 = 0.f, ay3 = 0.f;
        int j = beg;
        if (SH) {
            const unsigned int* base = (const unsigned int*)sh;
            for (; j + 8 <= end; j += 8) {
                unsigned int u[8];
                #pragma unroll
                for (int q = 0; q < 8; ++q)
                    u[q] = base[(size_t)list[j + q] * 64 + lane];
                ax0 += __uint_as_float(u[0] << 16) + __uint_as_float(u[4] << 16);
                ay0 += __uint_as_float(u[0] & 0xffff0000u) + __uint_as_float(u[4] & 0xffff0000u);
                ax1 += __uint_as_float(u[1] << 16) + __uint_as_float(u[5] << 16);
                ay1 += __uint_as_float(u[1] & 0xffff0000u) + __uint_as_float(u[5] & 0xffff0000u);
                ax2 += __uint_as_float(u[2] << 16) + __uint_as_float(u[6] << 16);
                ay2 += __uint_as_float(u[2] & 0xffff0000u) + __uint_as_float(u[6] & 0xffff0000u);
                ax3 += __uint_as_float(u[3] << 16) + __uint_as_float(u[7] << 16);
                ay3 += __uint_as_float(u[3] & 0xffff0000u) + __uint_as_float(u[7] & 0xffff0000u);
            }
            for (; j < end; ++j) {
                const unsigned int u = base[(size_t)list[j] * 64 + lane];
                ax0 += __uint_as_float(u << 16); ay0 += __uint_as_float(u & 0xffff0000u);
            }
        } else {
            for (; j + 4 <= end; j += 4) {
                const int e0 = list[j], e1 = list[j + 1], e2 = list[j + 2], e3 = list[j + 3];
                const float2 w0 = ((const float2*)(nef + (size_t)e0 * D))[lane];
                const float2 w1 = ((const float2*)(nef + (size_t)e1 * D))[lane];
                const float2 w2 = ((const float2*)(nef + (size_t)e2 * D))[lane];
                const float2 w3 = ((const float2*)(nef + (size_t)e3 * D))[lane];
                ax0 += w0.x; ay0 += w0.y; ax1 += w1.x; ay1 += w1.y;
                ax2 += w2.x; ay2 += w2.y; ax3 += w3.x; ay3 += w3.y;
            }
            for (; j < end; ++j) {
                const float2 w = ((const float2*)(nef + (size_t)list[j] * D))[lane];
                ax0 += w.x; ay0 += w.y;
            }
        }
        const float sx = (ax0 + ax1) + (ax2 + ax3);
        const float sy = (ay0 + ay1) + (ay2 + ay3);
        const float inv = 1.0f / ((float)deg + CNT_EPS);
        ((float2*)(edge_mean + (size_t)n * D))[lane] = make_float2(sx * inv, sy * inv);
    }
}

extern "C" void kernel_launch(void* const* d_in, const int* in_sizes, int n_in,
                              void* d_out, int out_size, void* d_ws, size_t ws_size,
                              hipStream_t stream) {
    const float* nodef   = (const float*)d_in[0];
    const float* edgef   = (const float*)d_in[1];
    const int*   eidx    = (const int*)d_in[2];
    const float* We      = (const float*)d_in[3];
    const float* be      = (const float*)d_in[4];
    const float* gamma_e = (const float*)d_in[5];
    const float* beta_e  = (const float*)d_in[6];
    const float* Wn      = (const float*)d_in[7];
    const float* bn      = (const float*)d_in[8];
    const float* gamma_n = (const float*)d_in[9];
    const float* beta_n  = (const float*)d_in[10];

    float* new_nodes = (float*)d_out;                      // also edge_mean buffer
    float* new_edges = (float*)d_out + (size_t)N_NODES * D;

    // workspace layout
    char* p = (char*)d_ws;
    __bf16* Wt  = (__bf16*)p;  p += 128 * 384 * 2;     // 98304
    __bf16* Wtn = (__bf16*)p;  p += 128 * 256 * 2;     // 65536
    int* cnt    = (int*)p;     p += (size_t)N_NODES * 4;
    int* excl   = (int*)p;     p += (size_t)N_NODES * 4;
    int* ctr    = (int*)p;     p += (size_t)N_NODES * 4;
    int* bsum   = (int*)p;     p += 2048;
    int* list   = (int*)p;     p += (size_t)2 * N_EDGES * 4;
    const size_t base_bytes = (size_t)(p - (char*)d_ws);
    const size_t shadow_bytes = (size_t)N_EDGES * D * 2;
    __bf16* shadow = nullptr;
    if (ws_size >= base_bytes + shadow_bytes) shadow = (__bf16*)p;

    hipMemsetAsync(cnt, 0, (size_t)N_NODES * sizeof(int), stream);
    hipMemsetAsync(ctr, 0, (size_t)N_NODES * sizeof(int), stream);

    prep_w<<<320, 256, 0, stream>>>(We, Wn, Wt, Wtn);

    edge_kernel<<<(N_EDGES + 127) / 128, 256, 0, stream>>>(
        nodef, edgef, eidx, Wt, be, gamma_e, beta_e, new_edges, shadow, cnt);

    scan1<<<NB, 256, 0, stream>>>(cnt, excl, bsum);
    scan2<<<1, 256, 0, stream>>>(bsum);
    fill_kernel<<<(N_EDGES + 255) / 256, 256, 0, stream>>>(eidx, excl, bsum, ctr, list);

    if (shadow)
        aggregate_kernel<true><<<4096, 256, 0, stream>>>(new_edges, shadow, excl, bsum, cnt, list, new_nodes);
    else
        aggregate_kernel<false><<<4096, 256, 0, stream>>>(new_edges, nullptr, excl, bsum, cnt, list, new_nodes);

    node_kernel<<<(N_NODES + 127) / 128, 256, 0, stream>>>(
        nodef, Wtn, bn, gamma_n, beta_n, new_nodes, new_nodes);
}